// Round 15
// baseline (237.309 us; speedup 1.0000x reference)
//
#include <hip/hip_runtime.h>
#include <math.h>

#define NLVL 10
#define TBL 65536
#define NHID 64
#define NIN 40
#define LDP 68   // padded LDS row stride (floats)

typedef __attribute__((ext_vector_type(8))) short bf16x8;
typedef __attribute__((ext_vector_type(4))) float f32x4;
typedef unsigned int uint;
typedef unsigned short ushort;

__device__ __forceinline__ float selu_f(float x) {
    return 1.0507009873554805f * (x > 0.0f ? x : 1.6732632423543772f * (__expf(x) - 1.0f));
}
__device__ __forceinline__ float fast_tanh(float x) {
    float xx = fminf(fmaxf(x, -15.0f), 15.0f);
    float t = __expf(2.0f * xx);
    return (t - 1.0f) / (t + 1.0f);
}
// truncation split: hi = top16 bits, lo = bf16-trunc of residual.
__device__ __forceinline__ short2 tsplit(float x) {
    uint u = __float_as_uint(x);
    short hi = (short)(u >> 16);
    float hif = __uint_as_float(u & 0xFFFF0000u);
    float lo = x - hif;
    short los = (short)(__float_as_uint(lo) >> 16);
    short2 s; s.x = hi; s.y = los;
    return s;
}

// Solve A x = b for 3x3 A (double precision, adjugate/Cramer).
__device__ __forceinline__ void solve3d(const double A[3][3], const double b[3], double x[3]) {
    double a00=A[0][0], a01=A[0][1], a02=A[0][2];
    double a10=A[1][0], a11=A[1][1], a12=A[1][2];
    double a20=A[2][0], a21=A[2][1], a22=A[2][2];
    double C00 =  (a11*a22 - a12*a21);
    double C01 = -(a10*a22 - a12*a20);
    double C02 =  (a10*a21 - a11*a20);
    double C10 = -(a01*a22 - a02*a21);
    double C11 =  (a00*a22 - a02*a20);
    double C12 = -(a00*a21 - a01*a20);
    double C20 =  (a01*a12 - a02*a11);
    double C21 = -(a00*a12 - a02*a10);
    double C22 =  (a00*a11 - a01*a10);
    double det = a00*C00 + a01*C01 + a02*C02;
    double inv = 1.0 / det;
    x[0] = (C00*b[0] + C10*b[1] + C20*b[2]) * inv;
    x[1] = (C01*b[0] + C11*b[1] + C21*b[2]) * inv;
    x[2] = (C02*b[0] + C12*b[1] + C22*b[2]) * inv;
}

__global__ void __launch_bounds__(256) zero_alpha_kernel(float* out, int V) {
    int i = blockIdx.x * blockDim.x + threadIdx.x;
    if (i < V) out[i] = 0.0f;
}

// Encode 2 consecutive levels (l0, l0+1) for one point.
__device__ __forceinline__ void enc2(const float4* __restrict__ tb4,
                                     float px, float py, float pz, float crf,
                                     int l0, float f[8]) {
    uint idx[2][8];
    float wt[2][8];
    #pragma unroll
    for (int h = 0; h < 2; ++h) {
        int l = l0 + h;
        float res = (float)(16 << l);
        float x0 = px*res, x1 = py*res, x2 = pz*res;
        float f0 = floorf(x0), f1 = floorf(x1), f2 = floorf(x2);
        float w0 = x0-f0, w1 = x1-f1, w2 = x2-f2;
        uint i0 = (uint)f0, i1 = (uint)f1, i2 = (uint)f2;
        #pragma unroll
        for (int cn = 0; cn < 8; ++cn) {
            uint cx = (uint)(cn & 1), cy = (uint)((cn >> 1) & 1), cz = (uint)((cn >> 2) & 1);
            idx[h][cn] = (((i0 + cx) * 1u) ^ ((i1 + cy) * 2654435761u) ^ ((i2 + cz) * 805459861u)) & 65535u;
            wt[h][cn] = (cx ? w0 : 1.0f - w0) * (cy ? w1 : 1.0f - w1) * (cz ? w2 : 1.0f - w2);
        }
    }
    float4 v[2][8];
    #pragma unroll
    for (int h = 0; h < 2; ++h)
        #pragma unroll
        for (int cn = 0; cn < 8; ++cn)
            v[h][cn] = tb4[(size_t)(l0+h)*TBL + idx[h][cn]];
    #pragma unroll
    for (int h = 0; h < 2; ++h) {
        float a0=0.f, a1=0.f, a2=0.f, a3=0.f;
        #pragma unroll
        for (int cn = 0; cn < 8; ++cn) {
            float w = wt[h][cn];
            a0 = fmaf(v[h][cn].x, w, a0);
            a1 = fmaf(v[h][cn].y, w, a1);
            a2 = fmaf(v[h][cn].z, w, a2);
            a3 = fmaf(v[h][cn].w, w, a3);
        }
        float sc = erff(rsqrtf(8.0f*(float)(l0+h)*crf + 1e-12f));
        f[h*4+0] = a0*sc; f[h*4+1] = a1*sc; f[h*4+2] = a2*sc; f[h*4+3] = a3*sc;
    }
}

// split f[8] into bf16 hi/lo planes and store as two 16B vectors
__device__ __forceinline__ void store_split8(const float f[8],
                                             ushort* __restrict__ fh,
                                             ushort* __restrict__ fl) {
    bf16x8 h8, l8;
    #pragma unroll
    for (int j = 0; j < 8; ++j) {
        short2 sp = tsplit(f[j]);
        h8[j] = sp.x; l8[j] = sp.y;
    }
    *reinterpret_cast<bf16x8*>(fh) = h8;
    *reinterpret_cast<bf16x8*>(fl) = l8;
}

// ---------------- Kernel 1: geometry + hash levels 0,1 ----------------
__global__ void __launch_bounds__(256) geom01_kernel(
    const float* __restrict__ vertices,
    const int*   __restrict__ indices,
    const float* __restrict__ center,
    const float* __restrict__ tables,
    float* __restrict__ aux,
    ushort* __restrict__ feats_hi,
    ushort* __restrict__ feats_lo, int T)
{
    int t = blockIdx.x * blockDim.x + threadIdx.x;
    if (t >= T) return;

    double p[4][3];
    #pragma unroll
    for (int v = 0; v < 4; ++v) {
        int vid = indices[t*4+v];
        p[v][0] = (double)vertices[vid*3+0];
        p[v][1] = (double)vertices[vid*3+1];
        p[v][2] = (double)vertices[vid*3+2];
    }

    double A[3][3], bb[3];
    double v0sq = p[0][0]*p[0][0] + p[0][1]*p[0][1] + p[0][2]*p[0][2];
    #pragma unroll
    for (int i = 0; i < 3; ++i) {
        #pragma unroll
        for (int j = 0; j < 3; ++j)
            A[i][j] = 2.0*(p[i+1][j] - p[0][j]) + (i==j ? 1e-6 : 0.0);
        bb[i] = p[i+1][0]*p[i+1][0] + p[i+1][1]*p[i+1][1] + p[i+1][2]*p[i+1][2] - v0sq;
    }
    double c[3];
    solve3d(A, bb, c);
    double dx0 = c[0]-p[0][0], dy0 = c[1]-p[0][1], dz0 = c[2]-p[0][2];
    double radius = sqrt(dx0*dx0 + dy0*dy0 + dz0*dz0);

    double E[3][3];
    #pragma unroll
    for (int i = 0; i < 3; ++i)
        #pragma unroll
        for (int j = 0; j < 3; ++j)
            E[i][j] = p[i+1][j] - p[0][j];
    double M[3][3], rhs[3];
    #pragma unroll
    for (int i = 0; i < 3; ++i) {
        #pragma unroll
        for (int k = 0; k < 3; ++k)
            M[i][k] = E[i][0]*E[k][0] + E[i][1]*E[k][1] + E[i][2]*E[k][2] + (i==k ? 1e-6 : 0.0);
        rhs[i] = E[i][0]*dx0 + E[i][1]*dy0 + E[i][2]*dz0;
    }
    double lam[3];
    solve3d(M, rhs, lam);
    double bary[4];
    bary[0] = 1.0 - lam[0] - lam[1] - lam[2];
    bary[1] = lam[0]; bary[2] = lam[1]; bary[3] = lam[2];
    double bs = 0.0;
    #pragma unroll
    for (int v = 0; v < 4; ++v) {
        bary[v] = fmin(fmax(bary[v], 0.0), 1.0);
        bs += bary[v];
    }
    bs = fmax(bs, 1e-6);
    double cc[3];
    #pragma unroll
    for (int j = 0; j < 3; ++j)
        cc[j] = (bary[0]*p[0][j] + bary[1]*p[1][j] + bary[2]*p[2][j] + bary[3]*p[3][j]) / bs;

    double xv[3];
    xv[0] = (cc[0] - (double)center[0]) * 0.5;
    xv[1] = (cc[1] - (double)center[1]) * 0.5;
    xv[2] = (cc[2] - (double)center[2]) * 0.5;
    double nrm = sqrt(xv[0]*xv[0] + xv[1]*xv[1] + xv[2]*xv[2]);
    double n = fmax(nrm, 1e-9);
    double cv[3], cs;
    if (n <= 1.0) {
        cv[0]=xv[0]; cv[1]=xv[1]; cv[2]=xv[2];
        cs = radius * 0.5;
    } else {
        double f = (2.0 - 1.0/n) / n;
        cv[0]=xv[0]*f; cv[1]=xv[1]*f; cv[2]=xv[2]*f;
        cs = radius * 0.5 / (n*n);
    }
    float crf = (float)(cs * 0.5);  // SCALE_MULTI

    float px = fminf(fmaxf((float)(cv[0]*0.25 + 0.5), 0.0f), 1.0f - 1e-6f);
    float py = fminf(fmaxf((float)(cv[1]*0.25 + 0.5), 0.0f), 1.0f - 1e-6f);
    float pz = fminf(fmaxf((float)(cv[2]*0.25 + 0.5), 0.0f), 1.0f - 1e-6f);

    float el = 0.0f;
    #pragma unroll
    for (int a = 0; a < 3; ++a)
        #pragma unroll
        for (int bq = a+1; bq < 4; ++bq) {
            float ddx = (float)(p[a][0]-p[bq][0]);
            float ddy = (float)(p[a][1]-p[bq][1]);
            float ddz = (float)(p[a][2]-p[bq][2]);
            el = fmaxf(el, sqrtf(ddx*ddx + ddy*ddy + ddz*ddz));
        }

    size_t st = (size_t)T;
    aux[0*st + t] = px;
    aux[1*st + t] = py;
    aux[2*st + t] = pz;
    aux[3*st + t] = crf;
    aux[4*st + t] = (float)cc[0];
    aux[5*st + t] = (float)cc[1];
    aux[6*st + t] = (float)cc[2];
    aux[7*st + t] = el;

    const float4* tb4 = reinterpret_cast<const float4*>(tables);
    float f01[8];
    enc2(tb4, px, py, pz, crf, 0, f01);
    store_split8(f01, feats_hi + (size_t)t*NIN, feats_lo + (size_t)t*NIN);
}

// ---------------- Kernel 2 (x4): hash levels (L0, L0+1) ----------------
template<int L0>
__global__ void __launch_bounds__(256) hash_pass_kernel(
    const float* __restrict__ tables,
    const float* __restrict__ aux,
    ushort* __restrict__ feats_hi,
    ushort* __restrict__ feats_lo, int T)
{
    int t = blockIdx.x * blockDim.x + threadIdx.x;
    if (t >= T) return;
    size_t st = (size_t)T;
    float px = aux[0*st + t];
    float py = aux[1*st + t];
    float pz = aux[2*st + t];
    float crf = aux[3*st + t];
    const float4* tb4 = reinterpret_cast<const float4*>(tables);

    float f[8];
    enc2(tb4, px, py, pz, crf, L0, f);
    store_split8(f, feats_hi + (size_t)t*NIN + L0*4, feats_lo + (size_t)t*NIN + L0*4);
}

// ---------------- Kernel 3: MFMA MLP + epilogue (software-pipelined) ----------------
__global__ void __launch_bounds__(256, 2) mlp_mfma_kernel(
    const ushort* __restrict__ feats_hi,
    const ushort* __restrict__ feats_lo,
    const float* __restrict__ aux,
    const float* __restrict__ vertices,
    const int*   __restrict__ indices,
    const float* __restrict__ W1, const float* __restrict__ b1,
    const float* __restrict__ W2, const float* __restrict__ b2,
    const float* __restrict__ W3, const float* __restrict__ b3,
    float* __restrict__ out, int T, int V)
{
    __shared__ __align__(16) float hts[4][16][LDP];   // per-wave 16x64(+pad) tile

    const int tid  = threadIdx.x;
    const int wid  = tid >> 6;
    const int lane = tid & 63;
    const int r    = lane & 15;   // n-index for B/C; m-row for A
    const int g    = lane >> 4;   // k-group

    // ---- weight fragments in registers (hi/lo split), once per wave ----
    bf16x8 w1h[2][4];
    bf16x8 w1l0[4];
    #pragma unroll
    for (int s = 0; s < 2; ++s)
        #pragma unroll
        for (int nt = 0; nt < 4; ++nt) {
            bf16x8 h, lo;
            #pragma unroll
            for (int j = 0; j < 8; ++j) {
                int k = s*32 + g*8 + j;
                float w = (k < NIN) ? W1[k*NHID + nt*16 + r] : 0.0f;
                short2 sp = tsplit(w);
                h[j] = sp.x; lo[j] = sp.y;
            }
            w1h[s][nt] = h;
            if (s == 0) w1l0[nt] = lo;
        }
    bf16x8 w2h[2][4], w2l[2][4];
    #pragma unroll
    for (int s = 0; s < 2; ++s)
        #pragma unroll
        for (int nt = 0; nt < 4; ++nt) {
            bf16x8 h, lo;
            #pragma unroll
            for (int j = 0; j < 8; ++j) {
                int k = s*32 + g*8 + j;
                float w = W2[k*NHID + nt*16 + r];
                short2 sp = tsplit(w);
                h[j] = sp.x; lo[j] = sp.y;
            }
            w2h[s][nt] = h; w2l[s][nt] = lo;
        }
    bf16x8 w3h[2], w3l[2];
    #pragma unroll
    for (int s = 0; s < 2; ++s) {
        bf16x8 h, lo;
        #pragma unroll
        for (int j = 0; j < 8; ++j) {
            int k = s*32 + g*8 + j;
            float w = (r < 13) ? W3[k*13 + r] : 0.0f;
            short2 sp = tsplit(w);
            h[j] = sp.x; lo[j] = sp.y;
        }
        w3h[s] = h; w3l[s] = lo;
    }
    float b1v[4], b2v[4];
    #pragma unroll
    for (int nt = 0; nt < 4; ++nt) { b1v[nt] = b1[nt*16 + r]; b2v[nt] = b2[nt*16 + r]; }
    float b3v = (r < 13) ? b3[r] : 0.0f;

    const size_t st = (size_t)T;
    const int nmt = (T + 15) >> 4;
    const int gw = blockIdx.x * 4 + wid;
    const int gstride = gridDim.x * 4;
    const bf16x8 zfrag = {0,0,0,0,0,0,0,0};

    if (gw >= nmt) return;

    // ---- preload A-frags for first tile ----
    bf16x8 ah0, al0, ah1;
    {
        int trow = gw*16 + r;
        bool rowok = trow < T;
        const ushort* fh = feats_hi + (size_t)trow * NIN;
        const ushort* fl = feats_lo + (size_t)trow * NIN;
        ah0 = rowok ? *reinterpret_cast<const bf16x8*>(fh + g*8) : zfrag;
        al0 = rowok ? *reinterpret_cast<const bf16x8*>(fl + g*8) : zfrag;
        ah1 = (rowok && g == 0) ? *reinterpret_cast<const bf16x8*>(fh + 32) : zfrag;
    }

    for (int mt = gw; mt < nmt; mt += gstride) {
        const int t0 = mt * 16;

        // ---- prefetch epilogue inputs for THIS tile (independent loads) ----
        const int te = t0 + (lane >> 2);   // tet for epilogue
        const int ev = lane & 3;           // vertex for epilogue
        const bool teok = te < T;
        int vid = teok ? indices[te*4 + ev] : 0;
        float el  = teok ? aux[7*st + te] : 0.0f;
        float cc0 = teok ? aux[4*st + te] : 0.0f;
        float cc1 = teok ? aux[5*st + te] : 0.0f;
        float cc2 = teok ? aux[6*st + te] : 0.0f;

        // ---- layer 1 MFMA (uses preloaded A-frags) ----
        __builtin_amdgcn_s_setprio(1);
        #pragma unroll
        for (int nt = 0; nt < 4; ++nt) {
            f32x4 acc = {0.f, 0.f, 0.f, 0.f};
            acc = __builtin_amdgcn_mfma_f32_16x16x32_bf16(ah0, w1h[0][nt], acc, 0, 0, 0);
            acc = __builtin_amdgcn_mfma_f32_16x16x32_bf16(ah0, w1l0[nt],  acc, 0, 0, 0);
            acc = __builtin_amdgcn_mfma_f32_16x16x32_bf16(al0, w1h[0][nt], acc, 0, 0, 0);
            acc = __builtin_amdgcn_mfma_f32_16x16x32_bf16(ah1, w1h[1][nt], acc, 0, 0, 0);
            #pragma unroll
            for (int q = 0; q < 4; ++q)
                hts[wid][g*4 + q][nt*16 + r] = selu_f(acc[q] + b1v[nt]);
        }
        __builtin_amdgcn_s_setprio(0);

        // ---- issue next tile's A-frag loads (hide under layers 2/3) ----
        const int mtn = mt + gstride;
        bf16x8 nah0 = zfrag, nal0 = zfrag, nah1 = zfrag;
        if (mtn < nmt) {
            int trow = mtn*16 + r;
            bool rowok = trow < T;
            const ushort* fh = feats_hi + (size_t)trow * NIN;
            const ushort* fl = feats_lo + (size_t)trow * NIN;
            if (rowok) {
                nah0 = *reinterpret_cast<const bf16x8*>(fh + g*8);
                nal0 = *reinterpret_cast<const bf16x8*>(fl + g*8);
                if (g == 0) nah1 = *reinterpret_cast<const bf16x8*>(fh + 32);
            }
        }

        // ---- issue dependent vertex loads now (vid arrived during layer 1) ----
        float pvx = vertices[vid*3+0];
        float pvy = vertices[vid*3+1];
        float pvz = vertices[vid*3+2];

        asm volatile("s_waitcnt lgkmcnt(0)" ::: "memory");

        // ---- layer 2: A-frags from LDS (float4 reads + trunc split) ----
        bf16x8 a2h[2], a2l[2];
        #pragma unroll
        for (int s = 0; s < 2; ++s) {
            float4 u0 = *reinterpret_cast<const float4*>(&hts[wid][r][s*32 + g*8]);
            float4 u1 = *reinterpret_cast<const float4*>(&hts[wid][r][s*32 + g*8 + 4]);
            bf16x8 h, lo;
            short2 sp;
            sp = tsplit(u0.x); h[0]=sp.x; lo[0]=sp.y;
            sp = tsplit(u0.y); h[1]=sp.x; lo[1]=sp.y;
            sp = tsplit(u0.z); h[2]=sp.x; lo[2]=sp.y;
            sp = tsplit(u0.w); h[3]=sp.x; lo[3]=sp.y;
            sp = tsplit(u1.x); h[4]=sp.x; lo[4]=sp.y;
            sp = tsplit(u1.y); h[5]=sp.x; lo[5]=sp.y;
            sp = tsplit(u1.z); h[6]=sp.x; lo[6]=sp.y;
            sp = tsplit(u1.w); h[7]=sp.x; lo[7]=sp.y;
            a2h[s] = h; a2l[s] = lo;
        }
        asm volatile("s_waitcnt lgkmcnt(0)" ::: "memory");
        float h2v[4][4];
        __builtin_amdgcn_s_setprio(1);
        #pragma unroll
        for (int nt = 0; nt < 4; ++nt) {
            f32x4 acc = {0.f, 0.f, 0.f, 0.f};
            #pragma unroll
            for (int s = 0; s < 2; ++s) {
                acc = __builtin_amdgcn_mfma_f32_16x16x32_bf16(a2h[s], w2h[s][nt], acc, 0, 0, 0);
                acc = __builtin_amdgcn_mfma_f32_16x16x32_bf16(a2h[s], w2l[s][nt], acc, 0, 0, 0);
                acc = __builtin_amdgcn_mfma_f32_16x16x32_bf16(a2l[s], w2h[s][nt], acc, 0, 0, 0);
            }
            #pragma unroll
            for (int q = 0; q < 4; ++q) h2v[nt][q] = selu_f(acc[q] + b2v[nt]);
        }
        __builtin_amdgcn_s_setprio(0);
        #pragma unroll
        for (int nt = 0; nt < 4; ++nt)
            #pragma unroll
            for (int q = 0; q < 4; ++q)
                hts[wid][g*4 + q][nt*16 + r] = h2v[nt][q];
        asm volatile("s_waitcnt lgkmcnt(0)" ::: "memory");

        // ---- layer 3: A-frags from LDS ----
        bf16x8 a3h[2], a3l[2];
        #pragma unroll
        for (int s = 0; s < 2; ++s) {
            float4 u0 = *reinterpret_cast<const float4*>(&hts[wid][r][s*32 + g*8]);
            float4 u1 = *reinterpret_cast<const float4*>(&hts[wid][r][s*32 + g*8 + 4]);
            bf16x8 h, lo;
            short2 sp;
            sp = tsplit(u0.x); h[0]=sp.x; lo[0]=sp.y;
            sp = tsplit(u0.y); h[1]=sp.x; lo[1]=sp.y;
            sp = tsplit(u0.z); h[2]=sp.x; lo[2]=sp.y;
            sp = tsplit(u0.w); h[3]=sp.x; lo[3]=sp.y;
            sp = tsplit(u1.x); h[4]=sp.x; lo[4]=sp.y;
            sp = tsplit(u1.y); h[5]=sp.x; lo[5]=sp.y;
            sp = tsplit(u1.z); h[6]=sp.x; lo[6]=sp.y;
            sp = tsplit(u1.w); h[7]=sp.x; lo[7]=sp.y;
            a3h[s] = h; a3l[s] = lo;
        }
        asm volatile("s_waitcnt lgkmcnt(0)" ::: "memory");
        {
            f32x4 acc = {0.f, 0.f, 0.f, 0.f};
            __builtin_amdgcn_s_setprio(1);
            #pragma unroll
            for (int s = 0; s < 2; ++s) {
                acc = __builtin_amdgcn_mfma_f32_16x16x32_bf16(a3h[s], w3h[s], acc, 0, 0, 0);
                acc = __builtin_amdgcn_mfma_f32_16x16x32_bf16(a3h[s], w3l[s], acc, 0, 0, 0);
                acc = __builtin_amdgcn_mfma_f32_16x16x32_bf16(a3l[s], w3h[s], acc, 0, 0, 0);
            }
            __builtin_amdgcn_s_setprio(0);
            #pragma unroll
            for (int q = 0; q < 4; ++q)
                hts[wid][g*4 + q][r] = acc[q] + b3v;   // o[n=r] of tet m=g*4+q
        }
        asm volatile("s_waitcnt lgkmcnt(0)" ::: "memory");

        // ---- epilogue: one (tet, vertex) per lane; all inputs already in regs ----
        if (teok) {
            const float* orow = hts[wid][lane >> 2];
            float4 o0 = *reinterpret_cast<const float4*>(&orow[0]);
            float4 o1 = *reinterpret_cast<const float4*>(&orow[4]);
            float4 o2 = *reinterpret_cast<const float4*>(&orow[8]);
            float o12 = orow[12];

            float dv = fminf(fmaxf(o0.x - 1.0f, -30.0f), 10.0f);
            float density = __expf(dv);
            float alpha = 1.0f - __expf(-density * el);
            int ab = __float_as_int(alpha);
            atomicMax((int*)out + vid, ab);

            float base0 = o0.y + 0.5f, base1 = o0.z + 0.5f, base2 = o0.w + 0.5f;
            float bc0 = fmaxf(base0, 0.0f), bc1 = fmaxf(base1, 0.0f), bc2 = fmaxf(base2, 0.0f);
            float g00 = bc0*fast_tanh(o1.x), g01 = bc0*fast_tanh(o1.y), g02 = bc0*fast_tanh(o1.z);
            float g10 = bc1*fast_tanh(o1.w), g11 = bc1*fast_tanh(o2.x), g12 = bc1*fast_tanh(o2.y);
            float g20 = bc2*fast_tanh(o2.z), g21 = bc2*fast_tanh(o2.w), g22 = bc2*fast_tanh(o12);

            float ox = pvx-cc0, oy = pvy-cc1, oz = pvz-cc2;
            float inv = rsqrtf(ox*ox + oy*oy + oz*oz + 1e-8f);
            float q0 = ox*inv, q1 = oy*inv, q2 = oz*inv;
            float* vout = out + V + (size_t)te * 12 + ev*3;
            vout[0] = base0 + g00*q0 + g01*q1 + g02*q2;
            vout[1] = base1 + g10*q0 + g11*q1 + g12*q2;
            vout[2] = base2 + g20*q0 + g21*q1 + g22*q2;
        }
        asm volatile("s_waitcnt lgkmcnt(0)" ::: "memory");

        ah0 = nah0; al0 = nal0; ah1 = nah1;
    }
}

// ---------------- Fallback fused kernel (used only if ws is too small) ----------------
__global__ void __launch_bounds__(256) tet_forward_fused(
    const float* __restrict__ vertices,
    const int*   __restrict__ indices,
    const float* __restrict__ center,
    const float* __restrict__ tables,
    const float* __restrict__ W1, const float* __restrict__ b1,
    const float* __restrict__ W2, const float* __restrict__ b2,
    const float* __restrict__ W3, const float* __restrict__ b3,
    float* __restrict__ out, int T, int V)
{
    int t = blockIdx.x * blockDim.x + threadIdx.x;
    if (t >= T) return;

    double p[4][3];
    int vv[4];
    #pragma unroll
    for (int v = 0; v < 4; ++v) {
        vv[v] = indices[t*4+v];
        p[v][0] = (double)vertices[vv[v]*3+0];
        p[v][1] = (double)vertices[vv[v]*3+1];
        p[v][2] = (double)vertices[vv[v]*3+2];
    }
    double A[3][3], bb[3];
    double v0sq = p[0][0]*p[0][0] + p[0][1]*p[0][1] + p[0][2]*p[0][2];
    #pragma unroll
    for (int i = 0; i < 3; ++i) {
        #pragma unroll
        for (int j = 0; j < 3; ++j)
            A[i][j] = 2.0*(p[i+1][j] - p[0][j]) + (i==j ? 1e-6 : 0.0);
        bb[i] = p[i+1][0]*p[i+1][0] + p[i+1][1]*p[i+1][1] + p[i+1][2]*p[i+1][2] - v0sq;
    }
    double c[3];
    solve3d(A, bb, c);
    double dx0 = c[0]-p[0][0], dy0 = c[1]-p[0][1], dz0 = c[2]-p[0][2];
    double radius = sqrt(dx0*dx0 + dy0*dy0 + dz0*dz0);
    double E[3][3];
    #pragma unroll
    for (int i = 0; i < 3; ++i)
        #pragma unroll
        for (int j = 0; j < 3; ++j)
            E[i][j] = p[i+1][j] - p[0][j];
    double M[3][3], rhs[3];
    #pragma unroll
    for (int i = 0; i < 3; ++i) {
        #pragma unroll
        for (int k = 0; k < 3; ++k)
            M[i][k] = E[i][0]*E[k][0] + E[i][1]*E[k][1] + E[i][2]*E[k][2] + (i==k ? 1e-6 : 0.0);
        rhs[i] = E[i][0]*dx0 + E[i][1]*dy0 + E[i][2]*dz0;
    }
    double lam[3];
    solve3d(M, rhs, lam);
    double bary[4];
    bary[0] = 1.0 - lam[0] - lam[1] - lam[2];
    bary[1] = lam[0]; bary[2] = lam[1]; bary[3] = lam[2];
    double bs = 0.0;
    #pragma unroll
    for (int v = 0; v < 4; ++v) { bary[v] = fmin(fmax(bary[v], 0.0), 1.0); bs += bary[v]; }
    bs = fmax(bs, 1e-6);
    double cc[3];
    #pragma unroll
    for (int j = 0; j < 3; ++j)
        cc[j] = (bary[0]*p[0][j] + bary[1]*p[1][j] + bary[2]*p[2][j] + bary[3]*p[3][j]) / bs;
    double xv[3];
    xv[0] = (cc[0] - (double)center[0]) * 0.5;
    xv[1] = (cc[1] - (double)center[1]) * 0.5;
    xv[2] = (cc[2] - (double)center[2]) * 0.5;
    double nrm = sqrt(xv[0]*xv[0] + xv[1]*xv[1] + xv[2]*xv[2]);
    double n = fmax(nrm, 1e-9);
    double cv[3], cs;
    if (n <= 1.0) { cv[0]=xv[0]; cv[1]=xv[1]; cv[2]=xv[2]; cs = radius * 0.5; }
    else { double f = (2.0 - 1.0/n) / n; cv[0]=xv[0]*f; cv[1]=xv[1]*f; cv[2]=xv[2]*f; cs = radius * 0.5 / (n*n); }
    float crf = (float)(cs * 0.5);
    float pos0 = fminf(fmaxf((float)(cv[0]*0.25 + 0.5), 0.0f), 1.0f - 1e-6f);
    float pos1 = fminf(fmaxf((float)(cv[1]*0.25 + 0.5), 0.0f), 1.0f - 1e-6f);
    float pos2 = fminf(fmaxf((float)(cv[2]*0.25 + 0.5), 0.0f), 1.0f - 1e-6f);

    float h0[NIN];
    float res = 16.0f;
    #pragma unroll
    for (int l = 0; l < NLVL; ++l) {
        float x0 = pos0*res, x1 = pos1*res, x2 = pos2*res;
        float f0 = floorf(x0), f1 = floorf(x1), f2 = floorf(x2);
        float w0 = x0-f0, w1 = x1-f1, w2 = x2-f2;
        unsigned i0 = (unsigned)f0, i1 = (unsigned)f1, i2 = (unsigned)f2;
        float a0=0.f, a1=0.f, a2=0.f, a3=0.f;
        #pragma unroll
        for (int cn = 0; cn < 8; ++cn) {
            unsigned cx = (unsigned)(cn & 1), cy = (unsigned)((cn >> 1) & 1), cz = (unsigned)((cn >> 2) & 1);
            unsigned hh = ((i0 + cx) * 1u) ^ ((i1 + cy) * 2654435761u) ^ ((i2 + cz) * 805459861u);
            hh &= 65535u;
            float wt = (cx ? w0 : 1.0f - w0) * (cy ? w1 : 1.0f - w1) * (cz ? w2 : 1.0f - w2);
            const float4 tv = *reinterpret_cast<const float4*>(tables + ((size_t)l*TBL + hh)*4);
            a0 = fmaf(tv.x, wt, a0); a1 = fmaf(tv.y, wt, a1);
            a2 = fmaf(tv.z, wt, a2); a3 = fmaf(tv.w, wt, a3);
        }
        float sc = erff(rsqrtf(8.0f*(float)l*crf + 1e-12f));
        h0[l*4+0] = a0*sc; h0[l*4+1] = a1*sc; h0[l*4+2] = a2*sc; h0[l*4+3] = a3*sc;
        res *= 2.0f;
    }

    float h1[NHID];
    #pragma unroll
    for (int j = 0; j < NHID; ++j) h1[j] = b1[j];
    #pragma unroll
    for (int i = 0; i < NIN; ++i) {
        float hi = h0[i];
        #pragma unroll
        for (int j = 0; j < NHID; ++j) h1[j] = fmaf(hi, W1[i*NHID + j], h1[j]);
    }
    #pragma unroll
    for (int j = 0; j < NHID; ++j) h1[j] = selu_f(h1[j]);

    float o[13];
    #pragma unroll
    for (int k = 0; k < 13; ++k) o[k] = b3[k];
    #pragma unroll
    for (int half = 0; half < 2; ++half) {
        float h2h[32];
        #pragma unroll
        for (int jj = 0; jj < 32; ++jj) h2h[jj] = b2[half*32 + jj];
        #pragma unroll
        for (int i = 0; i < NHID; ++i) {
            float hi = h1[i];
            #pragma unroll
            for (int jj = 0; jj < 32; ++jj)
                h2h[jj] = fmaf(hi, W2[i*NHID + half*32 + jj], h2h[jj]);
        }
        #pragma unroll
        for (int jj = 0; jj < 32; ++jj) {
            float hv = selu_f(h2h[jj]);
            #pragma unroll
            for (int k = 0; k < 13; ++k)
                o[k] = fmaf(hv, W3[(half*32 + jj)*13 + k], o[k]);
        }
    }

    float dv = fminf(fmaxf(o[0] - 1.0f, -30.0f), 10.0f);
    float density = __expf(dv);
    float el = 0.0f;
    #pragma unroll
    for (int a = 0; a < 3; ++a)
        #pragma unroll
        for (int bq = a+1; bq < 4; ++bq) {
            float ddx = (float)(p[a][0]-p[bq][0]);
            float ddy = (float)(p[a][1]-p[bq][1]);
            float ddz = (float)(p[a][2]-p[bq][2]);
            el = fmaxf(el, sqrtf(ddx*ddx + ddy*ddy + ddz*ddz));
        }
    float alpha = 1.0f - __expf(-density * el);
    int ab = __float_as_int(alpha);
    atomicMax((int*)out + vv[0], ab);
    atomicMax((int*)out + vv[1], ab);
    atomicMax((int*)out + vv[2], ab);
    atomicMax((int*)out + vv[3], ab);

    float base0 = o[1] + 0.5f, base1 = o[2] + 0.5f, base2 = o[3] + 0.5f;
    float bc0 = fmaxf(base0, 0.0f), bc1 = fmaxf(base1, 0.0f), bc2 = fmaxf(base2, 0.0f);
    float g00 = bc0*fast_tanh(o[4]),  g01 = bc0*fast_tanh(o[5]),  g02 = bc0*fast_tanh(o[6]);
    float g10 = bc1*fast_tanh(o[7]),  g11 = bc1*fast_tanh(o[8]),  g12 = bc1*fast_tanh(o[9]);
    float g20 = bc2*fast_tanh(o[10]), g21 = bc2*fast_tanh(o[11]), g22 = bc2*fast_tanh(o[12]);

    float* vout = out + V + (size_t)t * 12;
    #pragma unroll
    for (int v = 0; v < 4; ++v) {
        float ox = (float)(p[v][0]-cc[0]), oy = (float)(p[v][1]-cc[1]), oz = (float)(p[v][2]-cc[2]);
        float inv = rsqrtf(ox*ox + oy*oy + oz*oz + 1e-8f);
        float q0 = ox*inv, q1 = oy*inv, q2 = oz*inv;
        vout[v*3+0] = base0 + g00*q0 + g01*q1 + g02*q2;
        vout[v*3+1] = base1 + g10*q0 + g11*q1 + g12*q2;
        vout[v*3+2] = base2 + g20*q0 + g21*q1 + g22*q2;
    }
}

extern "C" void kernel_launch(void* const* d_in, const int* in_sizes, int n_in,
                              void* d_out, int out_size, void* d_ws, size_t ws_size,
                              hipStream_t stream) {
    const float* vertices = (const float*)d_in[0];
    const int*   indices  = (const int*)d_in[1];
    const float* center   = (const float*)d_in[2];
    const float* tables   = (const float*)d_in[3];
    const float* W1 = (const float*)d_in[4];
    const float* b1 = (const float*)d_in[5];
    const float* W2 = (const float*)d_in[6];
    const float* b2 = (const float*)d_in[7];
    const float* W3 = (const float*)d_in[8];
    const float* b3 = (const float*)d_in[9];
    int V = in_sizes[0] / 3;
    int T = in_sizes[1] / 4;
    float* out = (float*)d_out;

    hipLaunchKernelGGL(zero_alpha_kernel, dim3((V + 255) / 256), dim3(256), 0, stream, out, V);

    // ws: aux f32[8][T] (32B/tet) + feats_hi u16[T][40] (80B/tet) + feats_lo (80B/tet)
    size_t need = (size_t)T * 48 * sizeof(float);
    dim3 grid((T + 255) / 256), blk(256);
    if (ws_size >= need) {
        float* aux = (float*)d_ws;
        ushort* feats_hi = (ushort*)(aux + (size_t)T * 8);
        ushort* feats_lo = feats_hi + (size_t)T * NIN;
        hipLaunchKernelGGL(geom01_kernel, grid, blk, 0, stream,
                           vertices, indices, center, tables, aux, feats_hi, feats_lo, T);
        hipLaunchKernelGGL((hash_pass_kernel<2>), grid, blk, 0, stream, tables, aux, feats_hi, feats_lo, T);
        hipLaunchKernelGGL((hash_pass_kernel<4>), grid, blk, 0, stream, tables, aux, feats_hi, feats_lo, T);
        hipLaunchKernelGGL((hash_pass_kernel<6>), grid, blk, 0, stream, tables, aux, feats_hi, feats_lo, T);
        hipLaunchKernelGGL((hash_pass_kernel<8>), grid, blk, 0, stream, tables, aux, feats_hi, feats_lo, T);
        hipLaunchKernelGGL(mlp_mfma_kernel, dim3(1024), blk, 0, stream, feats_hi, feats_lo, aux,
                           vertices, indices, W1, b1, W2, b2, W3, b3, out, T, V);
    } else {
        hipLaunchKernelGGL(tet_forward_fused, grid, blk, 0, stream,
                           vertices, indices, center, tables, W1, b1, W2, b2, W3, b3, out, T, V);
    }
}

// Round 16
// 230.725 us; speedup vs baseline: 1.0285x; 1.0285x over previous
//
#include <hip/hip_runtime.h>
#include <math.h>

#define NLVL 10
#define TBL 65536
#define NHID 64
#define NIN 40
#define LDP 68   // padded LDS row stride (floats)

typedef __attribute__((ext_vector_type(8))) short bf16x8;
typedef __attribute__((ext_vector_type(4))) float f32x4;
typedef unsigned int uint;
typedef unsigned short ushort;

__device__ __forceinline__ float selu_f(float x) {
    return 1.0507009873554805f * (x > 0.0f ? x : 1.6732632423543772f * (__expf(x) - 1.0f));
}
__device__ __forceinline__ float fast_tanh(float x) {
    float xx = fminf(fmaxf(x, -15.0f), 15.0f);
    float t = __expf(2.0f * xx);
    return (t - 1.0f) / (t + 1.0f);
}
// truncation split: hi = top16 bits, lo = bf16-trunc of residual.
__device__ __forceinline__ short2 tsplit(float x) {
    uint u = __float_as_uint(x);
    short hi = (short)(u >> 16);
    float hif = __uint_as_float(u & 0xFFFF0000u);
    float lo = x - hif;
    short los = (short)(__float_as_uint(lo) >> 16);
    short2 s; s.x = hi; s.y = los;
    return s;
}

// Solve A x = b for 3x3 A (double precision, adjugate/Cramer).
__device__ __forceinline__ void solve3d(const double A[3][3], const double b[3], double x[3]) {
    double a00=A[0][0], a01=A[0][1], a02=A[0][2];
    double a10=A[1][0], a11=A[1][1], a12=A[1][2];
    double a20=A[2][0], a21=A[2][1], a22=A[2][2];
    double C00 =  (a11*a22 - a12*a21);
    double C01 = -(a10*a22 - a12*a20);
    double C02 =  (a10*a21 - a11*a20);
    double C10 = -(a01*a22 - a02*a21);
    double C11 =  (a00*a22 - a02*a20);
    double C12 = -(a00*a21 - a01*a20);
    double C20 =  (a01*a12 - a02*a11);
    double C21 = -(a00*a12 - a02*a10);
    double C22 =  (a00*a11 - a01*a10);
    double det = a00*C00 + a01*C01 + a02*C02;
    double inv = 1.0 / det;
    x[0] = (C00*b[0] + C10*b[1] + C20*b[2]) * inv;
    x[1] = (C01*b[0] + C11*b[1] + C21*b[2]) * inv;
    x[2] = (C02*b[0] + C12*b[1] + C22*b[2]) * inv;
}

__global__ void __launch_bounds__(256) zero_alpha_kernel(float* out, int V) {
    int i = blockIdx.x * blockDim.x + threadIdx.x;
    if (i < V) out[i] = 0.0f;
}

// Encode 2 consecutive levels (l0, l0+1) for one point.
__device__ __forceinline__ void enc2(const float4* __restrict__ tb4,
                                     float px, float py, float pz, float crf,
                                     int l0, float f[8]) {
    uint idx[2][8];
    float wt[2][8];
    #pragma unroll
    for (int h = 0; h < 2; ++h) {
        int l = l0 + h;
        float res = (float)(16 << l);
        float x0 = px*res, x1 = py*res, x2 = pz*res;
        float f0 = floorf(x0), f1 = floorf(x1), f2 = floorf(x2);
        float w0 = x0-f0, w1 = x1-f1, w2 = x2-f2;
        uint i0 = (uint)f0, i1 = (uint)f1, i2 = (uint)f2;
        #pragma unroll
        for (int cn = 0; cn < 8; ++cn) {
            uint cx = (uint)(cn & 1), cy = (uint)((cn >> 1) & 1), cz = (uint)((cn >> 2) & 1);
            idx[h][cn] = (((i0 + cx) * 1u) ^ ((i1 + cy) * 2654435761u) ^ ((i2 + cz) * 805459861u)) & 65535u;
            wt[h][cn] = (cx ? w0 : 1.0f - w0) * (cy ? w1 : 1.0f - w1) * (cz ? w2 : 1.0f - w2);
        }
    }
    float4 v[2][8];
    #pragma unroll
    for (int h = 0; h < 2; ++h)
        #pragma unroll
        for (int cn = 0; cn < 8; ++cn)
            v[h][cn] = tb4[(size_t)(l0+h)*TBL + idx[h][cn]];
    #pragma unroll
    for (int h = 0; h < 2; ++h) {
        float a0=0.f, a1=0.f, a2=0.f, a3=0.f;
        #pragma unroll
        for (int cn = 0; cn < 8; ++cn) {
            float w = wt[h][cn];
            a0 = fmaf(v[h][cn].x, w, a0);
            a1 = fmaf(v[h][cn].y, w, a1);
            a2 = fmaf(v[h][cn].z, w, a2);
            a3 = fmaf(v[h][cn].w, w, a3);
        }
        float sc = erff(rsqrtf(8.0f*(float)(l0+h)*crf + 1e-12f));
        f[h*4+0] = a0*sc; f[h*4+1] = a1*sc; f[h*4+2] = a2*sc; f[h*4+3] = a3*sc;
    }
}

// split f[8] into bf16 hi/lo planes and store as two 16B vectors
__device__ __forceinline__ void store_split8(const float f[8],
                                             ushort* __restrict__ fh,
                                             ushort* __restrict__ fl) {
    bf16x8 h8, l8;
    #pragma unroll
    for (int j = 0; j < 8; ++j) {
        short2 sp = tsplit(f[j]);
        h8[j] = sp.x; l8[j] = sp.y;
    }
    *reinterpret_cast<bf16x8*>(fh) = h8;
    *reinterpret_cast<bf16x8*>(fl) = l8;
}

// ---------------- Kernel 1: geometry + hash levels 0,1 ----------------
__global__ void __launch_bounds__(256) geom01_kernel(
    const float* __restrict__ vertices,
    const int*   __restrict__ indices,
    const float* __restrict__ center,
    const float* __restrict__ tables,
    float* __restrict__ aux,
    ushort* __restrict__ feats_hi,
    ushort* __restrict__ feats_lo, int T)
{
    int t = blockIdx.x * blockDim.x + threadIdx.x;
    if (t >= T) return;

    double p[4][3];
    #pragma unroll
    for (int v = 0; v < 4; ++v) {
        int vid = indices[t*4+v];
        p[v][0] = (double)vertices[vid*3+0];
        p[v][1] = (double)vertices[vid*3+1];
        p[v][2] = (double)vertices[vid*3+2];
    }

    double A[3][3], bb[3];
    double v0sq = p[0][0]*p[0][0] + p[0][1]*p[0][1] + p[0][2]*p[0][2];
    #pragma unroll
    for (int i = 0; i < 3; ++i) {
        #pragma unroll
        for (int j = 0; j < 3; ++j)
            A[i][j] = 2.0*(p[i+1][j] - p[0][j]) + (i==j ? 1e-6 : 0.0);
        bb[i] = p[i+1][0]*p[i+1][0] + p[i+1][1]*p[i+1][1] + p[i+1][2]*p[i+1][2] - v0sq;
    }
    double c[3];
    solve3d(A, bb, c);
    double dx0 = c[0]-p[0][0], dy0 = c[1]-p[0][1], dz0 = c[2]-p[0][2];
    double radius = sqrt(dx0*dx0 + dy0*dy0 + dz0*dz0);

    double E[3][3];
    #pragma unroll
    for (int i = 0; i < 3; ++i)
        #pragma unroll
        for (int j = 0; j < 3; ++j)
            E[i][j] = p[i+1][j] - p[0][j];
    double M[3][3], rhs[3];
    #pragma unroll
    for (int i = 0; i < 3; ++i) {
        #pragma unroll
        for (int k = 0; k < 3; ++k)
            M[i][k] = E[i][0]*E[k][0] + E[i][1]*E[k][1] + E[i][2]*E[k][2] + (i==k ? 1e-6 : 0.0);
        rhs[i] = E[i][0]*dx0 + E[i][1]*dy0 + E[i][2]*dz0;
    }
    double lam[3];
    solve3d(M, rhs, lam);
    double bary[4];
    bary[0] = 1.0 - lam[0] - lam[1] - lam[2];
    bary[1] = lam[0]; bary[2] = lam[1]; bary[3] = lam[2];
    double bs = 0.0;
    #pragma unroll
    for (int v = 0; v < 4; ++v) {
        bary[v] = fmin(fmax(bary[v], 0.0), 1.0);
        bs += bary[v];
    }
    bs = fmax(bs, 1e-6);
    double cc[3];
    #pragma unroll
    for (int j = 0; j < 3; ++j)
        cc[j] = (bary[0]*p[0][j] + bary[1]*p[1][j] + bary[2]*p[2][j] + bary[3]*p[3][j]) / bs;

    double xv[3];
    xv[0] = (cc[0] - (double)center[0]) * 0.5;
    xv[1] = (cc[1] - (double)center[1]) * 0.5;
    xv[2] = (cc[2] - (double)center[2]) * 0.5;
    double nrm = sqrt(xv[0]*xv[0] + xv[1]*xv[1] + xv[2]*xv[2]);
    double n = fmax(nrm, 1e-9);
    double cv[3], cs;
    if (n <= 1.0) {
        cv[0]=xv[0]; cv[1]=xv[1]; cv[2]=xv[2];
        cs = radius * 0.5;
    } else {
        double f = (2.0 - 1.0/n) / n;
        cv[0]=xv[0]*f; cv[1]=xv[1]*f; cv[2]=xv[2]*f;
        cs = radius * 0.5 / (n*n);
    }
    float crf = (float)(cs * 0.5);  // SCALE_MULTI

    float px = fminf(fmaxf((float)(cv[0]*0.25 + 0.5), 0.0f), 1.0f - 1e-6f);
    float py = fminf(fmaxf((float)(cv[1]*0.25 + 0.5), 0.0f), 1.0f - 1e-6f);
    float pz = fminf(fmaxf((float)(cv[2]*0.25 + 0.5), 0.0f), 1.0f - 1e-6f);

    float el = 0.0f;
    #pragma unroll
    for (int a = 0; a < 3; ++a)
        #pragma unroll
        for (int bq = a+1; bq < 4; ++bq) {
            float ddx = (float)(p[a][0]-p[bq][0]);
            float ddy = (float)(p[a][1]-p[bq][1]);
            float ddz = (float)(p[a][2]-p[bq][2]);
            el = fmaxf(el, sqrtf(ddx*ddx + ddy*ddy + ddz*ddz));
        }

    size_t st = (size_t)T;
    aux[0*st + t] = px;
    aux[1*st + t] = py;
    aux[2*st + t] = pz;
    aux[3*st + t] = crf;
    aux[4*st + t] = (float)cc[0];
    aux[5*st + t] = (float)cc[1];
    aux[6*st + t] = (float)cc[2];
    aux[7*st + t] = el;

    const float4* tb4 = reinterpret_cast<const float4*>(tables);
    float f01[8];
    enc2(tb4, px, py, pz, crf, 0, f01);
    store_split8(f01, feats_hi + (size_t)t*NIN, feats_lo + (size_t)t*NIN);
}

// ---------------- Kernel 2 (x4): hash levels (L0, L0+1) ----------------
template<int L0>
__global__ void __launch_bounds__(256) hash_pass_kernel(
    const float* __restrict__ tables,
    const float* __restrict__ aux,
    ushort* __restrict__ feats_hi,
    ushort* __restrict__ feats_lo, int T)
{
    int t = blockIdx.x * blockDim.x + threadIdx.x;
    if (t >= T) return;
    size_t st = (size_t)T;
    float px = aux[0*st + t];
    float py = aux[1*st + t];
    float pz = aux[2*st + t];
    float crf = aux[3*st + t];
    const float4* tb4 = reinterpret_cast<const float4*>(tables);

    float f[8];
    enc2(tb4, px, py, pz, crf, L0, f);
    store_split8(f, feats_hi + (size_t)t*NIN + L0*4, feats_lo + (size_t)t*NIN + L0*4);
}

// ---------------- Kernel 3: MFMA MLP + epilogue (weights in LDS) ----------------
// Weight B-fragments live in LDS, pre-split hi/lo and laid out so each MFMA's
// operand is a single conflict-free ds_read_b128: slot = set*64 + lane.
// Frees ~128 VGPRs vs register-resident weights -> 3 blocks/CU (12 waves).
__global__ void __launch_bounds__(256, 3) mlp_mfma_kernel(
    const ushort* __restrict__ feats_hi,
    const ushort* __restrict__ feats_lo,
    const float* __restrict__ aux,
    const float* __restrict__ vertices,
    const int*   __restrict__ indices,
    const float* __restrict__ W1, const float* __restrict__ b1,
    const float* __restrict__ W2, const float* __restrict__ b2,
    const float* __restrict__ W3, const float* __restrict__ b3,
    float* __restrict__ out, int T, int V)
{
    __shared__ __align__(16) float hts[4][16][LDP];   // 17.4 KB
    __shared__ bf16x8 sW1h[8*64];   // 8 KB  [ (s*4+nt)*64 + lane ]
    __shared__ bf16x8 sW1l[4*64];   // 4 KB  [ nt*64 + lane ]  (kstep0 only)
    __shared__ bf16x8 sW2h[8*64];   // 8 KB
    __shared__ bf16x8 sW2l[8*64];   // 8 KB
    __shared__ bf16x8 sW3h[2*64];   // 2 KB  [ s*64 + lane ]
    __shared__ bf16x8 sW3l[2*64];   // 2 KB

    const int tid  = threadIdx.x;
    const int wid  = tid >> 6;
    const int lane = tid & 63;
    const int r    = lane & 15;
    const int g    = lane >> 4;

    // ---- cooperative weight staging (once per block) ----
    for (int slot = tid; slot < 8*64; slot += 256) {
        int set = slot >> 6, l = slot & 63;
        int s = set >> 2, nt = set & 3;
        int rr = l & 15, gg = l >> 4;
        bf16x8 h, lo;
        #pragma unroll
        for (int j = 0; j < 8; ++j) {
            int k = s*32 + gg*8 + j;
            float w = (k < NIN) ? W1[k*NHID + nt*16 + rr] : 0.0f;
            short2 sp = tsplit(w);
            h[j] = sp.x; lo[j] = sp.y;
        }
        sW1h[slot] = h;
        if (s == 0) sW1l[nt*64 + l] = lo;
    }
    for (int slot = tid; slot < 8*64; slot += 256) {
        int set = slot >> 6, l = slot & 63;
        int s = set >> 2, nt = set & 3;
        int rr = l & 15, gg = l >> 4;
        bf16x8 h, lo;
        #pragma unroll
        for (int j = 0; j < 8; ++j) {
            int k = s*32 + gg*8 + j;
            float w = W2[k*NHID + nt*16 + rr];
            short2 sp = tsplit(w);
            h[j] = sp.x; lo[j] = sp.y;
        }
        sW2h[slot] = h;
        sW2l[slot] = lo;
    }
    for (int slot = tid; slot < 2*64; slot += 256) {
        int s = slot >> 6, l = slot & 63;
        int rr = l & 15, gg = l >> 4;
        bf16x8 h, lo;
        #pragma unroll
        for (int j = 0; j < 8; ++j) {
            int k = s*32 + gg*8 + j;
            float w = (rr < 13) ? W3[k*13 + rr] : 0.0f;
            short2 sp = tsplit(w);
            h[j] = sp.x; lo[j] = sp.y;
        }
        sW3h[slot] = h;
        sW3l[slot] = lo;
    }
    __syncthreads();

    float b1v[4], b2v[4];
    #pragma unroll
    for (int nt = 0; nt < 4; ++nt) { b1v[nt] = b1[nt*16 + r]; b2v[nt] = b2[nt*16 + r]; }
    float b3v = (r < 13) ? b3[r] : 0.0f;

    const size_t st = (size_t)T;
    const int nmt = (T + 15) >> 4;
    const int gw = blockIdx.x * 4 + wid;
    const int gstride = gridDim.x * 4;
    const bf16x8 zfrag = {0,0,0,0,0,0,0,0};

    if (gw >= nmt) return;

    // ---- preload A-frags for first tile ----
    bf16x8 ah0, al0, ah1;
    {
        int trow = gw*16 + r;
        bool rowok = trow < T;
        const ushort* fh = feats_hi + (size_t)trow * NIN;
        const ushort* fl = feats_lo + (size_t)trow * NIN;
        ah0 = rowok ? *reinterpret_cast<const bf16x8*>(fh + g*8) : zfrag;
        al0 = rowok ? *reinterpret_cast<const bf16x8*>(fl + g*8) : zfrag;
        ah1 = (rowok && g == 0) ? *reinterpret_cast<const bf16x8*>(fh + 32) : zfrag;
    }

    for (int mt = gw; mt < nmt; mt += gstride) {
        const int t0 = mt * 16;

        // ---- prefetch epilogue inputs for THIS tile ----
        const int te = t0 + (lane >> 2);
        const int ev = lane & 3;
        const bool teok = te < T;
        int vid = teok ? indices[te*4 + ev] : 0;
        float el  = teok ? aux[7*st + te] : 0.0f;
        float cc0 = teok ? aux[4*st + te] : 0.0f;
        float cc1 = teok ? aux[5*st + te] : 0.0f;
        float cc2 = teok ? aux[6*st + te] : 0.0f;

        // ---- layer 1 MFMA (weights streamed from LDS) ----
        __builtin_amdgcn_s_setprio(1);
        #pragma unroll
        for (int nt = 0; nt < 4; ++nt) {
            f32x4 acc = {0.f, 0.f, 0.f, 0.f};
            acc = __builtin_amdgcn_mfma_f32_16x16x32_bf16(ah0, sW1h[nt*64 + lane],       acc, 0, 0, 0);
            acc = __builtin_amdgcn_mfma_f32_16x16x32_bf16(ah0, sW1l[nt*64 + lane],       acc, 0, 0, 0);
            acc = __builtin_amdgcn_mfma_f32_16x16x32_bf16(al0, sW1h[nt*64 + lane],       acc, 0, 0, 0);
            acc = __builtin_amdgcn_mfma_f32_16x16x32_bf16(ah1, sW1h[(4+nt)*64 + lane],   acc, 0, 0, 0);
            #pragma unroll
            for (int q = 0; q < 4; ++q)
                hts[wid][g*4 + q][nt*16 + r] = selu_f(acc[q] + b1v[nt]);
        }
        __builtin_amdgcn_s_setprio(0);

        // ---- issue next tile's A-frag loads ----
        const int mtn = mt + gstride;
        bf16x8 nah0 = zfrag, nal0 = zfrag, nah1 = zfrag;
        if (mtn < nmt) {
            int trow = mtn*16 + r;
            bool rowok = trow < T;
            const ushort* fh = feats_hi + (size_t)trow * NIN;
            const ushort* fl = feats_lo + (size_t)trow * NIN;
            if (rowok) {
                nah0 = *reinterpret_cast<const bf16x8*>(fh + g*8);
                nal0 = *reinterpret_cast<const bf16x8*>(fl + g*8);
                if (g == 0) nah1 = *reinterpret_cast<const bf16x8*>(fh + 32);
            }
        }

        // ---- dependent vertex loads ----
        float pvx = vertices[vid*3+0];
        float pvy = vertices[vid*3+1];
        float pvz = vertices[vid*3+2];

        asm volatile("s_waitcnt lgkmcnt(0)" ::: "memory");

        // ---- layer 2: A-frags from LDS (float4 reads + trunc split) ----
        bf16x8 a2h[2], a2l[2];
        #pragma unroll
        for (int s = 0; s < 2; ++s) {
            float4 u0 = *reinterpret_cast<const float4*>(&hts[wid][r][s*32 + g*8]);
            float4 u1 = *reinterpret_cast<const float4*>(&hts[wid][r][s*32 + g*8 + 4]);
            bf16x8 h, lo;
            short2 sp;
            sp = tsplit(u0.x); h[0]=sp.x; lo[0]=sp.y;
            sp = tsplit(u0.y); h[1]=sp.x; lo[1]=sp.y;
            sp = tsplit(u0.z); h[2]=sp.x; lo[2]=sp.y;
            sp = tsplit(u0.w); h[3]=sp.x; lo[3]=sp.y;
            sp = tsplit(u1.x); h[4]=sp.x; lo[4]=sp.y;
            sp = tsplit(u1.y); h[5]=sp.x; lo[5]=sp.y;
            sp = tsplit(u1.z); h[6]=sp.x; lo[6]=sp.y;
            sp = tsplit(u1.w); h[7]=sp.x; lo[7]=sp.y;
            a2h[s] = h; a2l[s] = lo;
        }
        asm volatile("s_waitcnt lgkmcnt(0)" ::: "memory");
        float h2v[4][4];
        __builtin_amdgcn_s_setprio(1);
        #pragma unroll
        for (int nt = 0; nt < 4; ++nt) {
            f32x4 acc = {0.f, 0.f, 0.f, 0.f};
            #pragma unroll
            for (int s = 0; s < 2; ++s) {
                acc = __builtin_amdgcn_mfma_f32_16x16x32_bf16(a2h[s], sW2h[(s*4+nt)*64 + lane], acc, 0, 0, 0);
                acc = __builtin_amdgcn_mfma_f32_16x16x32_bf16(a2h[s], sW2l[(s*4+nt)*64 + lane], acc, 0, 0, 0);
                acc = __builtin_amdgcn_mfma_f32_16x16x32_bf16(a2l[s], sW2h[(s*4+nt)*64 + lane], acc, 0, 0, 0);
            }
            #pragma unroll
            for (int q = 0; q < 4; ++q) h2v[nt][q] = selu_f(acc[q] + b2v[nt]);
        }
        __builtin_amdgcn_s_setprio(0);
        #pragma unroll
        for (int nt = 0; nt < 4; ++nt)
            #pragma unroll
            for (int q = 0; q < 4; ++q)
                hts[wid][g*4 + q][nt*16 + r] = h2v[nt][q];
        asm volatile("s_waitcnt lgkmcnt(0)" ::: "memory");

        // ---- layer 3: A-frags from LDS ----
        bf16x8 a3h[2], a3l[2];
        #pragma unroll
        for (int s = 0; s < 2; ++s) {
            float4 u0 = *reinterpret_cast<const float4*>(&hts[wid][r][s*32 + g*8]);
            float4 u1 = *reinterpret_cast<const float4*>(&hts[wid][r][s*32 + g*8 + 4]);
            bf16x8 h, lo;
            short2 sp;
            sp = tsplit(u0.x); h[0]=sp.x; lo[0]=sp.y;
            sp = tsplit(u0.y); h[1]=sp.x; lo[1]=sp.y;
            sp = tsplit(u0.z); h[2]=sp.x; lo[2]=sp.y;
            sp = tsplit(u0.w); h[3]=sp.x; lo[3]=sp.y;
            sp = tsplit(u1.x); h[4]=sp.x; lo[4]=sp.y;
            sp = tsplit(u1.y); h[5]=sp.x; lo[5]=sp.y;
            sp = tsplit(u1.z); h[6]=sp.x; lo[6]=sp.y;
            sp = tsplit(u1.w); h[7]=sp.x; lo[7]=sp.y;
            a3h[s] = h; a3l[s] = lo;
        }
        asm volatile("s_waitcnt lgkmcnt(0)" ::: "memory");
        {
            f32x4 acc = {0.f, 0.f, 0.f, 0.f};
            __builtin_amdgcn_s_setprio(1);
            #pragma unroll
            for (int s = 0; s < 2; ++s) {
                acc = __builtin_amdgcn_mfma_f32_16x16x32_bf16(a3h[s], sW3h[s*64 + lane], acc, 0, 0, 0);
                acc = __builtin_amdgcn_mfma_f32_16x16x32_bf16(a3h[s], sW3l[s*64 + lane], acc, 0, 0, 0);
                acc = __builtin_amdgcn_mfma_f32_16x16x32_bf16(a3l[s], sW3h[s*64 + lane], acc, 0, 0, 0);
            }
            __builtin_amdgcn_s_setprio(0);
            #pragma unroll
            for (int q = 0; q < 4; ++q)
                hts[wid][g*4 + q][r] = acc[q] + b3v;
        }
        asm volatile("s_waitcnt lgkmcnt(0)" ::: "memory");

        // ---- epilogue: one (tet, vertex) per lane ----
        if (teok) {
            const float* orow = hts[wid][lane >> 2];
            float4 o0 = *reinterpret_cast<const float4*>(&orow[0]);
            float4 o1 = *reinterpret_cast<const float4*>(&orow[4]);
            float4 o2 = *reinterpret_cast<const float4*>(&orow[8]);
            float o12 = orow[12];

            float dv = fminf(fmaxf(o0.x - 1.0f, -30.0f), 10.0f);
            float density = __expf(dv);
            float alpha = 1.0f - __expf(-density * el);
            int ab = __float_as_int(alpha);
            atomicMax((int*)out + vid, ab);

            float base0 = o0.y + 0.5f, base1 = o0.z + 0.5f, base2 = o0.w + 0.5f;
            float bc0 = fmaxf(base0, 0.0f), bc1 = fmaxf(base1, 0.0f), bc2 = fmaxf(base2, 0.0f);
            float g00 = bc0*fast_tanh(o1.x), g01 = bc0*fast_tanh(o1.y), g02 = bc0*fast_tanh(o1.z);
            float g10 = bc1*fast_tanh(o1.w), g11 = bc1*fast_tanh(o2.x), g12 = bc1*fast_tanh(o2.y);
            float g20 = bc2*fast_tanh(o2.z), g21 = bc2*fast_tanh(o2.w), g22 = bc2*fast_tanh(o12);

            float ox = pvx-cc0, oy = pvy-cc1, oz = pvz-cc2;
            float inv = rsqrtf(ox*ox + oy*oy + oz*oz + 1e-8f);
            float q0 = ox*inv, q1 = oy*inv, q2 = oz*inv;
            float* vout = out + V + (size_t)te * 12 + ev*3;
            vout[0] = base0 + g00*q0 + g01*q1 + g02*q2;
            vout[1] = base1 + g10*q0 + g11*q1 + g12*q2;
            vout[2] = base2 + g20*q0 + g21*q1 + g22*q2;
        }
        asm volatile("s_waitcnt lgkmcnt(0)" ::: "memory");

        ah0 = nah0; al0 = nal0; ah1 = nah1;
    }
}

// ---------------- Fallback fused kernel (used only if ws is too small) ----------------
__global__ void __launch_bounds__(256) tet_forward_fused(
    const float* __restrict__ vertices,
    const int*   __restrict__ indices,
    const float* __restrict__ center,
    const float* __restrict__ tables,
    const float* __restrict__ W1, const float* __restrict__ b1,
    const float* __restrict__ W2, const float* __restrict__ b2,
    const float* __restrict__ W3, const float* __restrict__ b3,
    float* __restrict__ out, int T, int V)
{
    int t = blockIdx.x * blockDim.x + threadIdx.x;
    if (t >= T) return;

    double p[4][3];
    int vv[4];
    #pragma unroll
    for (int v = 0; v < 4; ++v) {
        vv[v] = indices[t*4+v];
        p[v][0] = (double)vertices[vv[v]*3+0];
        p[v][1] = (double)vertices[vv[v]*3+1];
        p[v][2] = (double)vertices[vv[v]*3+2];
    }
    double A[3][3], bb[3];
    double v0sq = p[0][0]*p[0][0] + p[0][1]*p[0][1] + p[0][2]*p[0][2];
    #pragma unroll
    for (int i = 0; i < 3; ++i) {
        #pragma unroll
        for (int j = 0; j < 3; ++j)
            A[i][j] = 2.0*(p[i+1][j] - p[0][j]) + (i==j ? 1e-6 : 0.0);
        bb[i] = p[i+1][0]*p[i+1][0] + p[i+1][1]*p[i+1][1] + p[i+1][2]*p[i+1][2] - v0sq;
    }
    double c[3];
    solve3d(A, bb, c);
    double dx0 = c[0]-p[0][0], dy0 = c[1]-p[0][1], dz0 = c[2]-p[0][2];
    double radius = sqrt(dx0*dx0 + dy0*dy0 + dz0*dz0);
    double E[3][3];
    #pragma unroll
    for (int i = 0; i < 3; ++i)
        #pragma unroll
        for (int j = 0; j < 3; ++j)
            E[i][j] = p[i+1][j] - p[0][j];
    double M[3][3], rhs[3];
    #pragma unroll
    for (int i = 0; i < 3; ++i) {
        #pragma unroll
        for (int k = 0; k < 3; ++k)
            M[i][k] = E[i][0]*E[k][0] + E[i][1]*E[k][1] + E[i][2]*E[k][2] + (i==k ? 1e-6 : 0.0);
        rhs[i] = E[i][0]*dx0 + E[i][1]*dy0 + E[i][2]*dz0;
    }
    double lam[3];
    solve3d(M, rhs, lam);
    double bary[4];
    bary[0] = 1.0 - lam[0] - lam[1] - lam[2];
    bary[1] = lam[0]; bary[2] = lam[1]; bary[3] = lam[2];
    double bs = 0.0;
    #pragma unroll
    for (int v = 0; v < 4; ++v) { bary[v] = fmin(fmax(bary[v], 0.0), 1.0); bs += bary[v]; }
    bs = fmax(bs, 1e-6);
    double cc[3];
    #pragma unroll
    for (int j = 0; j < 3; ++j)
        cc[j] = (bary[0]*p[0][j] + bary[1]*p[1][j] + bary[2]*p[2][j] + bary[3]*p[3][j]) / bs;
    double xv[3];
    xv[0] = (cc[0] - (double)center[0]) * 0.5;
    xv[1] = (cc[1] - (double)center[1]) * 0.5;
    xv[2] = (cc[2] - (double)center[2]) * 0.5;
    double nrm = sqrt(xv[0]*xv[0] + xv[1]*xv[1] + xv[2]*xv[2]);
    double n = fmax(nrm, 1e-9);
    double cv[3], cs;
    if (n <= 1.0) { cv[0]=xv[0]; cv[1]=xv[1]; cv[2]=xv[2]; cs = radius * 0.5; }
    else { double f = (2.0 - 1.0/n) / n; cv[0]=xv[0]*f; cv[1]=xv[1]*f; cv[2]=xv[2]*f; cs = radius * 0.5 / (n*n); }
    float crf = (float)(cs * 0.5);
    float pos0 = fminf(fmaxf((float)(cv[0]*0.25 + 0.5), 0.0f), 1.0f - 1e-6f);
    float pos1 = fminf(fmaxf((float)(cv[1]*0.25 + 0.5), 0.0f), 1.0f - 1e-6f);
    float pos2 = fminf(fmaxf((float)(cv[2]*0.25 + 0.5), 0.0f), 1.0f - 1e-6f);

    float h0[NIN];
    float res = 16.0f;
    #pragma unroll
    for (int l = 0; l < NLVL; ++l) {
        float x0 = pos0*res, x1 = pos1*res, x2 = pos2*res;
        float f0 = floorf(x0), f1 = floorf(x1), f2 = floorf(x2);
        float w0 = x0-f0, w1 = x1-f1, w2 = x2-f2;
        unsigned i0 = (unsigned)f0, i1 = (unsigned)f1, i2 = (unsigned)f2;
        float a0=0.f, a1=0.f, a2=0.f, a3=0.f;
        #pragma unroll
        for (int cn = 0; cn < 8; ++cn) {
            unsigned cx = (unsigned)(cn & 1), cy = (unsigned)((cn >> 1) & 1), cz = (unsigned)((cn >> 2) & 1);
            unsigned hh = ((i0 + cx) * 1u) ^ ((i1 + cy) * 2654435761u) ^ ((i2 + cz) * 805459861u);
            hh &= 65535u;
            float wt = (cx ? w0 : 1.0f - w0) * (cy ? w1 : 1.0f - w1) * (cz ? w2 : 1.0f - w2);
            const float4 tv = *reinterpret_cast<const float4*>(tables + ((size_t)l*TBL + hh)*4);
            a0 = fmaf(tv.x, wt, a0); a1 = fmaf(tv.y, wt, a1);
            a2 = fmaf(tv.z, wt, a2); a3 = fmaf(tv.w, wt, a3);
        }
        float sc = erff(rsqrtf(8.0f*(float)l*crf + 1e-12f));
        h0[l*4+0] = a0*sc; h0[l*4+1] = a1*sc; h0[l*4+2] = a2*sc; h0[l*4+3] = a3*sc;
        res *= 2.0f;
    }

    float h1[NHID];
    #pragma unroll
    for (int j = 0; j < NHID; ++j) h1[j] = b1[j];
    #pragma unroll
    for (int i = 0; i < NIN; ++i) {
        float hi = h0[i];
        #pragma unroll
        for (int j = 0; j < NHID; ++j) h1[j] = fmaf(hi, W1[i*NHID + j], h1[j]);
    }
    #pragma unroll
    for (int j = 0; j < NHID; ++j) h1[j] = selu_f(h1[j]);

    float o[13];
    #pragma unroll
    for (int k = 0; k < 13; ++k) o[k] = b3[k];
    #pragma unroll
    for (int half = 0; half < 2; ++half) {
        float h2h[32];
        #pragma unroll
        for (int jj = 0; jj < 32; ++jj) h2h[jj] = b2[half*32 + jj];
        #pragma unroll
        for (int i = 0; i < NHID; ++i) {
            float hi = h1[i];
            #pragma unroll
            for (int jj = 0; jj < 32; ++jj)
                h2h[jj] = fmaf(hi, W2[i*NHID + half*32 + jj], h2h[jj]);
        }
        #pragma unroll
        for (int jj = 0; jj < 32; ++jj) {
            float hv = selu_f(h2h[jj]);
            #pragma unroll
            for (int k = 0; k < 13; ++k)
                o[k] = fmaf(hv, W3[(half*32 + jj)*13 + k], o[k]);
        }
    }

    float dv = fminf(fmaxf(o[0] - 1.0f, -30.0f), 10.0f);
    float density = __expf(dv);
    float el = 0.0f;
    #pragma unroll
    for (int a = 0; a < 3; ++a)
        #pragma unroll
        for (int bq = a+1; bq < 4; ++bq) {
            float ddx = (float)(p[a][0]-p[bq][0]);
            float ddy = (float)(p[a][1]-p[bq][1]);
            float ddz = (float)(p[a][2]-p[bq][2]);
            el = fmaxf(el, sqrtf(ddx*ddx + ddy*ddy + ddz*ddz));
        }
    float alpha = 1.0f - __expf(-density * el);
    int ab = __float_as_int(alpha);
    atomicMax((int*)out + vv[0], ab);
    atomicMax((int*)out + vv[1], ab);
    atomicMax((int*)out + vv[2], ab);
    atomicMax((int*)out + vv[3], ab);

    float base0 = o[1] + 0.5f, base1 = o[2] + 0.5f, base2 = o[3] + 0.5f;
    float bc0 = fmaxf(base0, 0.0f), bc1 = fmaxf(base1, 0.0f), bc2 = fmaxf(base2, 0.0f);
    float g00 = bc0*fast_tanh(o[4]),  g01 = bc0*fast_tanh(o[5]),  g02 = bc0*fast_tanh(o[6]);
    float g10 = bc1*fast_tanh(o[7]),  g11 = bc1*fast_tanh(o[8]),  g12 = bc1*fast_tanh(o[9]);
    float g20 = bc2*fast_tanh(o[10]), g21 = bc2*fast_tanh(o[11]), g22 = bc2*fast_tanh(o[12]);

    float* vout = out + V + (size_t)t * 12;
    #pragma unroll
    for (int v = 0; v < 4; ++v) {
        float ox = (float)(p[v][0]-cc[0]), oy = (float)(p[v][1]-cc[1]), oz = (float)(p[v][2]-cc[2]);
        float inv = rsqrtf(ox*ox + oy*oy + oz*oz + 1e-8f);
        float q0 = ox*inv, q1 = oy*inv, q2 = oz*inv;
        vout[v*3+0] = base0 + g00*q0 + g01*q1 + g02*q2;
        vout[v*3+1] = base1 + g10*q0 + g11*q1 + g12*q2;
        vout[v*3+2] = base2 + g20*q0 + g21*q1 + g22*q2;
    }
}

extern "C" void kernel_launch(void* const* d_in, const int* in_sizes, int n_in,
                              void* d_out, int out_size, void* d_ws, size_t ws_size,
                              hipStream_t stream) {
    const float* vertices = (const float*)d_in[0];
    const int*   indices  = (const int*)d_in[1];
    const float* center   = (const float*)d_in[2];
    const float* tables   = (const float*)d_in[3];
    const float* W1 = (const float*)d_in[4];
    const float* b1 = (const float*)d_in[5];
    const float* W2 = (const float*)d_in[6];
    const float* b2 = (const float*)d_in[7];
    const float* W3 = (const float*)d_in[8];
    const float* b3 = (const float*)d_in[9];
    int V = in_sizes[0] / 3;
    int T = in_sizes[1] / 4;
    float* out = (float*)d_out;

    hipLaunchKernelGGL(zero_alpha_kernel, dim3((V + 255) / 256), dim3(256), 0, stream, out, V);

    // ws: aux f32[8][T] (32B/tet) + feats_hi u16[T][40] (80B/tet) + feats_lo (80B/tet)
    size_t need = (size_t)T * 48 * sizeof(float);
    dim3 grid((T + 255) / 256), blk(256);
    if (ws_size >= need) {
        float* aux = (float*)d_ws;
        ushort* feats_hi = (ushort*)(aux + (size_t)T * 8);
        ushort* feats_lo = feats_hi + (size_t)T * NIN;
        hipLaunchKernelGGL(geom01_kernel, grid, blk, 0, stream,
                           vertices, indices, center, tables, aux, feats_hi, feats_lo, T);
        hipLaunchKernelGGL((hash_pass_kernel<2>), grid, blk, 0, stream, tables, aux, feats_hi, feats_lo, T);
        hipLaunchKernelGGL((hash_pass_kernel<4>), grid, blk, 0, stream, tables, aux, feats_hi, feats_lo, T);
        hipLaunchKernelGGL((hash_pass_kernel<6>), grid, blk, 0, stream, tables, aux, feats_hi, feats_lo, T);
        hipLaunchKernelGGL((hash_pass_kernel<8>), grid, blk, 0, stream, tables, aux, feats_hi, feats_lo, T);
        hipLaunchKernelGGL(mlp_mfma_kernel, dim3(768), blk, 0, stream, feats_hi, feats_lo, aux,
                           vertices, indices, W1, b1, W2, b2, W3, b3, out, T, V);
    } else {
        hipLaunchKernelGGL(tet_forward_fused, grid, blk, 0, stream,
                           vertices, indices, center, tables, W1, b1, W2, b2, W3, b3, out, T, V);
    }
}

// Round 17
// 230.466 us; speedup vs baseline: 1.0297x; 1.0011x over previous
//
#include <hip/hip_runtime.h>
#include <math.h>

#define NLVL 10
#define TBL 65536
#define NHID 64
#define NIN 40
#define LDP 68   // padded LDS row stride (floats)

typedef __attribute__((ext_vector_type(8))) short bf16x8;
typedef __attribute__((ext_vector_type(4))) float f32x4;
typedef unsigned int uint;
typedef unsigned short ushort;

__device__ __forceinline__ float selu_f(float x) {
    return 1.0507009873554805f * (x > 0.0f ? x : 1.6732632423543772f * (__expf(x) - 1.0f));
}
__device__ __forceinline__ float fast_tanh(float x) {
    float xx = fminf(fmaxf(x, -15.0f), 15.0f);
    float t = __expf(2.0f * xx);
    return (t - 1.0f) / (t + 1.0f);
}
// round-nearest f32 -> bf16 bits
__device__ __forceinline__ unsigned short f2bf(float x) {
    unsigned u = __float_as_uint(x);
    unsigned r = (u + 0x7FFFu + ((u >> 16) & 1u)) >> 16;
    return (unsigned short)r;
}
// truncation split: hi = top16 bits, lo = bf16-trunc of residual.
__device__ __forceinline__ short2 tsplit(float x) {
    uint u = __float_as_uint(x);
    short hi = (short)(u >> 16);
    float hif = __uint_as_float(u & 0xFFFF0000u);
    float lo = x - hif;
    short los = (short)(__float_as_uint(lo) >> 16);
    short2 s; s.x = hi; s.y = los;
    return s;
}

// Solve A x = b for 3x3 A (double precision, adjugate/Cramer).
__device__ __forceinline__ void solve3d(const double A[3][3], const double b[3], double x[3]) {
    double a00=A[0][0], a01=A[0][1], a02=A[0][2];
    double a10=A[1][0], a11=A[1][1], a12=A[1][2];
    double a20=A[2][0], a21=A[2][1], a22=A[2][2];
    double C00 =  (a11*a22 - a12*a21);
    double C01 = -(a10*a22 - a12*a20);
    double C02 =  (a10*a21 - a11*a20);
    double C10 = -(a01*a22 - a02*a21);
    double C11 =  (a00*a22 - a02*a20);
    double C12 = -(a00*a21 - a01*a20);
    double C20 =  (a01*a12 - a02*a11);
    double C21 = -(a00*a12 - a02*a10);
    double C22 =  (a00*a11 - a01*a10);
    double det = a00*C00 + a01*C01 + a02*C02;
    double inv = 1.0 / det;
    x[0] = (C00*b[0] + C10*b[1] + C20*b[2]) * inv;
    x[1] = (C01*b[0] + C11*b[1] + C21*b[2]) * inv;
    x[2] = (C02*b[0] + C12*b[1] + C22*b[2]) * inv;
}

__global__ void __launch_bounds__(256) zero_alpha_kernel(float* out, int V) {
    int i = blockIdx.x * blockDim.x + threadIdx.x;
    if (i < V) out[i] = 0.0f;
}

// Encode 2 consecutive levels (l0, l0+1) for one point.
__device__ __forceinline__ void enc2(const float4* __restrict__ tb4,
                                     float px, float py, float pz, float crf,
                                     int l0, float f[8]) {
    uint idx[2][8];
    float wt[2][8];
    #pragma unroll
    for (int h = 0; h < 2; ++h) {
        int l = l0 + h;
        float res = (float)(16 << l);
        float x0 = px*res, x1 = py*res, x2 = pz*res;
        float f0 = floorf(x0), f1 = floorf(x1), f2 = floorf(x2);
        float w0 = x0-f0, w1 = x1-f1, w2 = x2-f2;
        uint i0 = (uint)f0, i1 = (uint)f1, i2 = (uint)f2;
        #pragma unroll
        for (int cn = 0; cn < 8; ++cn) {
            uint cx = (uint)(cn & 1), cy = (uint)((cn >> 1) & 1), cz = (uint)((cn >> 2) & 1);
            idx[h][cn] = (((i0 + cx) * 1u) ^ ((i1 + cy) * 2654435761u) ^ ((i2 + cz) * 805459861u)) & 65535u;
            wt[h][cn] = (cx ? w0 : 1.0f - w0) * (cy ? w1 : 1.0f - w1) * (cz ? w2 : 1.0f - w2);
        }
    }
    float4 v[2][8];
    #pragma unroll
    for (int h = 0; h < 2; ++h)
        #pragma unroll
        for (int cn = 0; cn < 8; ++cn)
            v[h][cn] = tb4[(size_t)(l0+h)*TBL + idx[h][cn]];
    #pragma unroll
    for (int h = 0; h < 2; ++h) {
        float a0=0.f, a1=0.f, a2=0.f, a3=0.f;
        #pragma unroll
        for (int cn = 0; cn < 8; ++cn) {
            float w = wt[h][cn];
            a0 = fmaf(v[h][cn].x, w, a0);
            a1 = fmaf(v[h][cn].y, w, a1);
            a2 = fmaf(v[h][cn].z, w, a2);
            a3 = fmaf(v[h][cn].w, w, a3);
        }
        float sc = erff(rsqrtf(8.0f*(float)(l0+h)*crf + 1e-12f));
        f[h*4+0] = a0*sc; f[h*4+1] = a1*sc; f[h*4+2] = a2*sc; f[h*4+3] = a3*sc;
    }
}

// split f[8] into bf16 hi/lo planes and store as two 16B vectors
__device__ __forceinline__ void store_split8(const float f[8],
                                             ushort* __restrict__ fh,
                                             ushort* __restrict__ fl) {
    bf16x8 h8, l8;
    #pragma unroll
    for (int j = 0; j < 8; ++j) {
        short2 sp = tsplit(f[j]);
        h8[j] = sp.x; l8[j] = sp.y;
    }
    *reinterpret_cast<bf16x8*>(fh) = h8;
    *reinterpret_cast<bf16x8*>(fl) = l8;
}

// ---------------- Kernel 1: geometry + hash levels 0,1 ----------------
__global__ void __launch_bounds__(256) geom01_kernel(
    const float* __restrict__ vertices,
    const int*   __restrict__ indices,
    const float* __restrict__ center,
    const float* __restrict__ tables,
    float* __restrict__ aux,
    ushort* __restrict__ feats_hi,
    ushort* __restrict__ feats_lo, int T)
{
    int t = blockIdx.x * blockDim.x + threadIdx.x;
    if (t >= T) return;

    double p[4][3];
    #pragma unroll
    for (int v = 0; v < 4; ++v) {
        int vid = indices[t*4+v];
        p[v][0] = (double)vertices[vid*3+0];
        p[v][1] = (double)vertices[vid*3+1];
        p[v][2] = (double)vertices[vid*3+2];
    }

    double A[3][3], bb[3];
    double v0sq = p[0][0]*p[0][0] + p[0][1]*p[0][1] + p[0][2]*p[0][2];
    #pragma unroll
    for (int i = 0; i < 3; ++i) {
        #pragma unroll
        for (int j = 0; j < 3; ++j)
            A[i][j] = 2.0*(p[i+1][j] - p[0][j]) + (i==j ? 1e-6 : 0.0);
        bb[i] = p[i+1][0]*p[i+1][0] + p[i+1][1]*p[i+1][1] + p[i+1][2]*p[i+1][2] - v0sq;
    }
    double c[3];
    solve3d(A, bb, c);
    double dx0 = c[0]-p[0][0], dy0 = c[1]-p[0][1], dz0 = c[2]-p[0][2];
    double radius = sqrt(dx0*dx0 + dy0*dy0 + dz0*dz0);

    double E[3][3];
    #pragma unroll
    for (int i = 0; i < 3; ++i)
        #pragma unroll
        for (int j = 0; j < 3; ++j)
            E[i][j] = p[i+1][j] - p[0][j];
    double M[3][3], rhs[3];
    #pragma unroll
    for (int i = 0; i < 3; ++i) {
        #pragma unroll
        for (int k = 0; k < 3; ++k)
            M[i][k] = E[i][0]*E[k][0] + E[i][1]*E[k][1] + E[i][2]*E[k][2] + (i==k ? 1e-6 : 0.0);
        rhs[i] = E[i][0]*dx0 + E[i][1]*dy0 + E[i][2]*dz0;
    }
    double lam[3];
    solve3d(M, rhs, lam);
    double bary[4];
    bary[0] = 1.0 - lam[0] - lam[1] - lam[2];
    bary[1] = lam[0]; bary[2] = lam[1]; bary[3] = lam[2];
    double bs = 0.0;
    #pragma unroll
    for (int v = 0; v < 4; ++v) {
        bary[v] = fmin(fmax(bary[v], 0.0), 1.0);
        bs += bary[v];
    }
    bs = fmax(bs, 1e-6);
    double cc[3];
    #pragma unroll
    for (int j = 0; j < 3; ++j)
        cc[j] = (bary[0]*p[0][j] + bary[1]*p[1][j] + bary[2]*p[2][j] + bary[3]*p[3][j]) / bs;

    double xv[3];
    xv[0] = (cc[0] - (double)center[0]) * 0.5;
    xv[1] = (cc[1] - (double)center[1]) * 0.5;
    xv[2] = (cc[2] - (double)center[2]) * 0.5;
    double nrm = sqrt(xv[0]*xv[0] + xv[1]*xv[1] + xv[2]*xv[2]);
    double n = fmax(nrm, 1e-9);
    double cv[3], cs;
    if (n <= 1.0) {
        cv[0]=xv[0]; cv[1]=xv[1]; cv[2]=xv[2];
        cs = radius * 0.5;
    } else {
        double f = (2.0 - 1.0/n) / n;
        cv[0]=xv[0]*f; cv[1]=xv[1]*f; cv[2]=xv[2]*f;
        cs = radius * 0.5 / (n*n);
    }
    float crf = (float)(cs * 0.5);  // SCALE_MULTI

    float px = fminf(fmaxf((float)(cv[0]*0.25 + 0.5), 0.0f), 1.0f - 1e-6f);
    float py = fminf(fmaxf((float)(cv[1]*0.25 + 0.5), 0.0f), 1.0f - 1e-6f);
    float pz = fminf(fmaxf((float)(cv[2]*0.25 + 0.5), 0.0f), 1.0f - 1e-6f);

    float el = 0.0f;
    #pragma unroll
    for (int a = 0; a < 3; ++a)
        #pragma unroll
        for (int bq = a+1; bq < 4; ++bq) {
            float ddx = (float)(p[a][0]-p[bq][0]);
            float ddy = (float)(p[a][1]-p[bq][1]);
            float ddz = (float)(p[a][2]-p[bq][2]);
            el = fmaxf(el, sqrtf(ddx*ddx + ddy*ddy + ddz*ddz));
        }

    size_t st = (size_t)T;
    aux[0*st + t] = px;
    aux[1*st + t] = py;
    aux[2*st + t] = pz;
    aux[3*st + t] = crf;
    aux[4*st + t] = (float)cc[0];
    aux[5*st + t] = (float)cc[1];
    aux[6*st + t] = (float)cc[2];
    aux[7*st + t] = el;

    const float4* tb4 = reinterpret_cast<const float4*>(tables);
    float f01[8];
    enc2(tb4, px, py, pz, crf, 0, f01);
    store_split8(f01, feats_hi + (size_t)t*NIN, feats_lo + (size_t)t*NIN);
}

// ---------------- Kernel 2 (x4): hash levels (L0, L0+1) ----------------
template<int L0>
__global__ void __launch_bounds__(256) hash_pass_kernel(
    const float* __restrict__ tables,
    const float* __restrict__ aux,
    ushort* __restrict__ feats_hi,
    ushort* __restrict__ feats_lo, int T)
{
    int t = blockIdx.x * blockDim.x + threadIdx.x;
    if (t >= T) return;
    size_t st = (size_t)T;
    float px = aux[0*st + t];
    float py = aux[1*st + t];
    float pz = aux[2*st + t];
    float crf = aux[3*st + t];
    const float4* tb4 = reinterpret_cast<const float4*>(tables);

    float f[8];
    enc2(tb4, px, py, pz, crf, L0, f);
    store_split8(f, feats_hi + (size_t)t*NIN + L0*4, feats_lo + (size_t)t*NIN + L0*4);
}

// ---------------- Kernel 3: MFMA MLP + epilogue (weights in LDS) ----------------
// Layer-2/3 activations are round-nearest bf16 (no residual fragment): weights
// keep hi/lo split so weight precision ~2^-16; activation rounding adds ~2^-9.
__global__ void __launch_bounds__(256, 3) mlp_mfma_kernel(
    const ushort* __restrict__ feats_hi,
    const ushort* __restrict__ feats_lo,
    const float* __restrict__ aux,
    const float* __restrict__ vertices,
    const int*   __restrict__ indices,
    const float* __restrict__ W1, const float* __restrict__ b1,
    const float* __restrict__ W2, const float* __restrict__ b2,
    const float* __restrict__ W3, const float* __restrict__ b3,
    float* __restrict__ out, int T, int V)
{
    __shared__ __align__(16) float hts[4][16][LDP];   // 17.4 KB
    __shared__ bf16x8 sW1h[8*64];   // 8 KB  [ (s*4+nt)*64 + lane ]
    __shared__ bf16x8 sW1l[4*64];   // 4 KB  [ nt*64 + lane ]  (kstep0 only)
    __shared__ bf16x8 sW2h[8*64];   // 8 KB
    __shared__ bf16x8 sW2l[8*64];   // 8 KB
    __shared__ bf16x8 sW3h[2*64];   // 2 KB
    __shared__ bf16x8 sW3l[2*64];   // 2 KB

    const int tid  = threadIdx.x;
    const int wid  = tid >> 6;
    const int lane = tid & 63;
    const int r    = lane & 15;
    const int g    = lane >> 4;

    // ---- cooperative weight staging (once per block) ----
    for (int slot = tid; slot < 8*64; slot += 256) {
        int set = slot >> 6, l = slot & 63;
        int s = set >> 2, nt = set & 3;
        int rr = l & 15, gg = l >> 4;
        bf16x8 h, lo;
        #pragma unroll
        for (int j = 0; j < 8; ++j) {
            int k = s*32 + gg*8 + j;
            float w = (k < NIN) ? W1[k*NHID + nt*16 + rr] : 0.0f;
            short2 sp = tsplit(w);
            h[j] = sp.x; lo[j] = sp.y;
        }
        sW1h[slot] = h;
        if (s == 0) sW1l[nt*64 + l] = lo;
    }
    for (int slot = tid; slot < 8*64; slot += 256) {
        int set = slot >> 6, l = slot & 63;
        int s = set >> 2, nt = set & 3;
        int rr = l & 15, gg = l >> 4;
        bf16x8 h, lo;
        #pragma unroll
        for (int j = 0; j < 8; ++j) {
            int k = s*32 + gg*8 + j;
            float w = W2[k*NHID + nt*16 + rr];
            short2 sp = tsplit(w);
            h[j] = sp.x; lo[j] = sp.y;
        }
        sW2h[slot] = h;
        sW2l[slot] = lo;
    }
    for (int slot = tid; slot < 2*64; slot += 256) {
        int s = slot >> 6, l = slot & 63;
        int rr = l & 15, gg = l >> 4;
        bf16x8 h, lo;
        #pragma unroll
        for (int j = 0; j < 8; ++j) {
            int k = s*32 + gg*8 + j;
            float w = (rr < 13) ? W3[k*13 + rr] : 0.0f;
            short2 sp = tsplit(w);
            h[j] = sp.x; lo[j] = sp.y;
        }
        sW3h[slot] = h;
        sW3l[slot] = lo;
    }
    __syncthreads();

    float b1v[4], b2v[4];
    #pragma unroll
    for (int nt = 0; nt < 4; ++nt) { b1v[nt] = b1[nt*16 + r]; b2v[nt] = b2[nt*16 + r]; }
    float b3v = (r < 13) ? b3[r] : 0.0f;

    const size_t st = (size_t)T;
    const int nmt = (T + 15) >> 4;
    const int gw = blockIdx.x * 4 + wid;
    const int gstride = gridDim.x * 4;
    const bf16x8 zfrag = {0,0,0,0,0,0,0,0};

    if (gw >= nmt) return;

    // ---- preload A-frags for first tile ----
    bf16x8 ah0, al0, ah1;
    {
        int trow = gw*16 + r;
        bool rowok = trow < T;
        const ushort* fh = feats_hi + (size_t)trow * NIN;
        const ushort* fl = feats_lo + (size_t)trow * NIN;
        ah0 = rowok ? *reinterpret_cast<const bf16x8*>(fh + g*8) : zfrag;
        al0 = rowok ? *reinterpret_cast<const bf16x8*>(fl + g*8) : zfrag;
        ah1 = (rowok && g == 0) ? *reinterpret_cast<const bf16x8*>(fh + 32) : zfrag;
    }

    for (int mt = gw; mt < nmt; mt += gstride) {
        const int t0 = mt * 16;

        // ---- prefetch epilogue inputs for THIS tile ----
        const int te = t0 + (lane >> 2);
        const int ev = lane & 3;
        const bool teok = te < T;
        int vid = teok ? indices[te*4 + ev] : 0;
        float el  = teok ? aux[7*st + te] : 0.0f;
        float cc0 = teok ? aux[4*st + te] : 0.0f;
        float cc1 = teok ? aux[5*st + te] : 0.0f;
        float cc2 = teok ? aux[6*st + te] : 0.0f;

        // ---- layer 1 MFMA (weights streamed from LDS) ----
        __builtin_amdgcn_s_setprio(1);
        #pragma unroll
        for (int nt = 0; nt < 4; ++nt) {
            f32x4 acc = {0.f, 0.f, 0.f, 0.f};
            acc = __builtin_amdgcn_mfma_f32_16x16x32_bf16(ah0, sW1h[nt*64 + lane],       acc, 0, 0, 0);
            acc = __builtin_amdgcn_mfma_f32_16x16x32_bf16(ah0, sW1l[nt*64 + lane],       acc, 0, 0, 0);
            acc = __builtin_amdgcn_mfma_f32_16x16x32_bf16(al0, sW1h[nt*64 + lane],       acc, 0, 0, 0);
            acc = __builtin_amdgcn_mfma_f32_16x16x32_bf16(ah1, sW1h[(4+nt)*64 + lane],   acc, 0, 0, 0);
            #pragma unroll
            for (int q = 0; q < 4; ++q)
                hts[wid][g*4 + q][nt*16 + r] = selu_f(acc[q] + b1v[nt]);
        }
        __builtin_amdgcn_s_setprio(0);

        // ---- issue next tile's A-frag loads ----
        const int mtn = mt + gstride;
        bf16x8 nah0 = zfrag, nal0 = zfrag, nah1 = zfrag;
        if (mtn < nmt) {
            int trow = mtn*16 + r;
            bool rowok = trow < T;
            const ushort* fh = feats_hi + (size_t)trow * NIN;
            const ushort* fl = feats_lo + (size_t)trow * NIN;
            if (rowok) {
                nah0 = *reinterpret_cast<const bf16x8*>(fh + g*8);
                nal0 = *reinterpret_cast<const bf16x8*>(fl + g*8);
                if (g == 0) nah1 = *reinterpret_cast<const bf16x8*>(fh + 32);
            }
        }

        // ---- dependent vertex loads ----
        float pvx = vertices[vid*3+0];
        float pvy = vertices[vid*3+1];
        float pvz = vertices[vid*3+2];

        asm volatile("s_waitcnt lgkmcnt(0)" ::: "memory");

        // ---- layer 2: A-frags from LDS, round-nearest bf16 (no residual) ----
        bf16x8 a2[2];
        #pragma unroll
        for (int s = 0; s < 2; ++s) {
            float4 u0 = *reinterpret_cast<const float4*>(&hts[wid][r][s*32 + g*8]);
            float4 u1 = *reinterpret_cast<const float4*>(&hts[wid][r][s*32 + g*8 + 4]);
            bf16x8 h;
            h[0] = (short)f2bf(u0.x); h[1] = (short)f2bf(u0.y);
            h[2] = (short)f2bf(u0.z); h[3] = (short)f2bf(u0.w);
            h[4] = (short)f2bf(u1.x); h[5] = (short)f2bf(u1.y);
            h[6] = (short)f2bf(u1.z); h[7] = (short)f2bf(u1.w);
            a2[s] = h;
        }
        asm volatile("s_waitcnt lgkmcnt(0)" ::: "memory");
        float h2v[4][4];
        __builtin_amdgcn_s_setprio(1);
        #pragma unroll
        for (int nt = 0; nt < 4; ++nt) {
            f32x4 acc = {0.f, 0.f, 0.f, 0.f};
            #pragma unroll
            for (int s = 0; s < 2; ++s) {
                acc = __builtin_amdgcn_mfma_f32_16x16x32_bf16(a2[s], sW2h[(s*4+nt)*64 + lane], acc, 0, 0, 0);
                acc = __builtin_amdgcn_mfma_f32_16x16x32_bf16(a2[s], sW2l[(s*4+nt)*64 + lane], acc, 0, 0, 0);
            }
            #pragma unroll
            for (int q = 0; q < 4; ++q) h2v[nt][q] = selu_f(acc[q] + b2v[nt]);
        }
        __builtin_amdgcn_s_setprio(0);
        #pragma unroll
        for (int nt = 0; nt < 4; ++nt)
            #pragma unroll
            for (int q = 0; q < 4; ++q)
                hts[wid][g*4 + q][nt*16 + r] = h2v[nt][q];
        asm volatile("s_waitcnt lgkmcnt(0)" ::: "memory");

        // ---- layer 3: A-frags from LDS, round-nearest bf16 ----
        bf16x8 a3[2];
        #pragma unroll
        for (int s = 0; s < 2; ++s) {
            float4 u0 = *reinterpret_cast<const float4*>(&hts[wid][r][s*32 + g*8]);
            float4 u1 = *reinterpret_cast<const float4*>(&hts[wid][r][s*32 + g*8 + 4]);
            bf16x8 h;
            h[0] = (short)f2bf(u0.x); h[1] = (short)f2bf(u0.y);
            h[2] = (short)f2bf(u0.z); h[3] = (short)f2bf(u0.w);
            h[4] = (short)f2bf(u1.x); h[5] = (short)f2bf(u1.y);
            h[6] = (short)f2bf(u1.z); h[7] = (short)f2bf(u1.w);
            a3[s] = h;
        }
        asm volatile("s_waitcnt lgkmcnt(0)" ::: "memory");
        {
            f32x4 acc = {0.f, 0.f, 0.f, 0.f};
            __builtin_amdgcn_s_setprio(1);
            #pragma unroll
            for (int s = 0; s < 2; ++s) {
                acc = __builtin_amdgcn_mfma_f32_16x16x32_bf16(a3[s], sW3h[s*64 + lane], acc, 0, 0, 0);
                acc = __builtin_amdgcn_mfma_f32_16x16x32_bf16(a3[s], sW3l[s*64 + lane], acc, 0, 0, 0);
            }
            __builtin_amdgcn_s_setprio(0);
            #pragma unroll
            for (int q = 0; q < 4; ++q)
                hts[wid][g*4 + q][r] = acc[q] + b3v;
        }
        asm volatile("s_waitcnt lgkmcnt(0)" ::: "memory");

        // ---- epilogue: one (tet, vertex) per lane ----
        if (teok) {
            const float* orow = hts[wid][lane >> 2];
            float4 o0 = *reinterpret_cast<const float4*>(&orow[0]);
            float4 o1 = *reinterpret_cast<const float4*>(&orow[4]);
            float4 o2 = *reinterpret_cast<const float4*>(&orow[8]);
            float o12 = orow[12];

            float dv = fminf(fmaxf(o0.x - 1.0f, -30.0f), 10.0f);
            float density = __expf(dv);
            float alpha = 1.0f - __expf(-density * el);
            int ab = __float_as_int(alpha);
            atomicMax((int*)out + vid, ab);

            float base0 = o0.y + 0.5f, base1 = o0.z + 0.5f, base2 = o0.w + 0.5f;
            float bc0 = fmaxf(base0, 0.0f), bc1 = fmaxf(base1, 0.0f), bc2 = fmaxf(base2, 0.0f);
            float g00 = bc0*fast_tanh(o1.x), g01 = bc0*fast_tanh(o1.y), g02 = bc0*fast_tanh(o1.z);
            float g10 = bc1*fast_tanh(o1.w), g11 = bc1*fast_tanh(o2.x), g12 = bc1*fast_tanh(o2.y);
            float g20 = bc2*fast_tanh(o2.z), g21 = bc2*fast_tanh(o2.w), g22 = bc2*fast_tanh(o12);

            float ox = pvx-cc0, oy = pvy-cc1, oz = pvz-cc2;
            float inv = rsqrtf(ox*ox + oy*oy + oz*oz + 1e-8f);
            float q0 = ox*inv, q1 = oy*inv, q2 = oz*inv;
            float* vout = out + V + (size_t)te * 12 + ev*3;
            vout[0] = base0 + g00*q0 + g01*q1 + g02*q2;
            vout[1] = base1 + g10*q0 + g11*q1 + g12*q2;
            vout[2] = base2 + g20*q0 + g21*q1 + g22*q2;
        }
        asm volatile("s_waitcnt lgkmcnt(0)" ::: "memory");

        ah0 = nah0; al0 = nal0; ah1 = nah1;
    }
}

// ---------------- Fallback fused kernel (used only if ws is too small) ----------------
__global__ void __launch_bounds__(256) tet_forward_fused(
    const float* __restrict__ vertices,
    const int*   __restrict__ indices,
    const float* __restrict__ center,
    const float* __restrict__ tables,
    const float* __restrict__ W1, const float* __restrict__ b1,
    const float* __restrict__ W2, const float* __restrict__ b2,
    const float* __restrict__ W3, const float* __restrict__ b3,
    float* __restrict__ out, int T, int V)
{
    int t = blockIdx.x * blockDim.x + threadIdx.x;
    if (t >= T) return;

    double p[4][3];
    int vv[4];
    #pragma unroll
    for (int v = 0; v < 4; ++v) {
        vv[v] = indices[t*4+v];
        p[v][0] = (double)vertices[vv[v]*3+0];
        p[v][1] = (double)vertices[vv[v]*3+1];
        p[v][2] = (double)vertices[vv[v]*3+2];
    }
    double A[3][3], bb[3];
    double v0sq = p[0][0]*p[0][0] + p[0][1]*p[0][1] + p[0][2]*p[0][2];
    #pragma unroll
    for (int i = 0; i < 3; ++i) {
        #pragma unroll
        for (int j = 0; j < 3; ++j)
            A[i][j] = 2.0*(p[i+1][j] - p[0][j]) + (i==j ? 1e-6 : 0.0);
        bb[i] = p[i+1][0]*p[i+1][0] + p[i+1][1]*p[i+1][1] + p[i+1][2]*p[i+1][2] - v0sq;
    }
    double c[3];
    solve3d(A, bb, c);
    double dx0 = c[0]-p[0][0], dy0 = c[1]-p[0][1], dz0 = c[2]-p[0][2];
    double radius = sqrt(dx0*dx0 + dy0*dy0 + dz0*dz0);
    double E[3][3];
    #pragma unroll
    for (int i = 0; i < 3; ++i)
        #pragma unroll
        for (int j = 0; j < 3; ++j)
            E[i][j] = p[i+1][j] - p[0][j];
    double M[3][3], rhs[3];
    #pragma unroll
    for (int i = 0; i < 3; ++i) {
        #pragma unroll
        for (int k = 0; k < 3; ++k)
            M[i][k] = E[i][0]*E[k][0] + E[i][1]*E[k][1] + E[i][2]*E[k][2] + (i==k ? 1e-6 : 0.0);
        rhs[i] = E[i][0]*dx0 + E[i][1]*dy0 + E[i][2]*dz0;
    }
    double lam[3];
    solve3d(M, rhs, lam);
    double bary[4];
    bary[0] = 1.0 - lam[0] - lam[1] - lam[2];
    bary[1] = lam[0]; bary[2] = lam[1]; bary[3] = lam[2];
    double bs = 0.0;
    #pragma unroll
    for (int v = 0; v < 4; ++v) { bary[v] = fmin(fmax(bary[v], 0.0), 1.0); bs += bary[v]; }
    bs = fmax(bs, 1e-6);
    double cc[3];
    #pragma unroll
    for (int j = 0; j < 3; ++j)
        cc[j] = (bary[0]*p[0][j] + bary[1]*p[1][j] + bary[2]*p[2][j] + bary[3]*p[3][j]) / bs;
    double xv[3];
    xv[0] = (cc[0] - (double)center[0]) * 0.5;
    xv[1] = (cc[1] - (double)center[1]) * 0.5;
    xv[2] = (cc[2] - (double)center[2]) * 0.5;
    double nrm = sqrt(xv[0]*xv[0] + xv[1]*xv[1] + xv[2]*xv[2]);
    double n = fmax(nrm, 1e-9);
    double cv[3], cs;
    if (n <= 1.0) { cv[0]=xv[0]; cv[1]=xv[1]; cv[2]=xv[2]; cs = radius * 0.5; }
    else { double f = (2.0 - 1.0/n) / n; cv[0]=xv[0]*f; cv[1]=xv[1]*f; cv[2]=xv[2]*f; cs = radius * 0.5 / (n*n); }
    float crf = (float)(cs * 0.5);
    float pos0 = fminf(fmaxf((float)(cv[0]*0.25 + 0.5), 0.0f), 1.0f - 1e-6f);
    float pos1 = fminf(fmaxf((float)(cv[1]*0.25 + 0.5), 0.0f), 1.0f - 1e-6f);
    float pos2 = fminf(fmaxf((float)(cv[2]*0.25 + 0.5), 0.0f), 1.0f - 1e-6f);

    float h0[NIN];
    float res = 16.0f;
    #pragma unroll
    for (int l = 0; l < NLVL; ++l) {
        float x0 = pos0*res, x1 = pos1*res, x2 = pos2*res;
        float f0 = floorf(x0), f1 = floorf(x1), f2 = floorf(x2);
        float w0 = x0-f0, w1 = x1-f1, w2 = x2-f2;
        unsigned i0 = (unsigned)f0, i1 = (unsigned)f1, i2 = (unsigned)f2;
        float a0=0.f, a1=0.f, a2=0.f, a3=0.f;
        #pragma unroll
        for (int cn = 0; cn < 8; ++cn) {
            unsigned cx = (unsigned)(cn & 1), cy = (unsigned)((cn >> 1) & 1), cz = (unsigned)((cn >> 2) & 1);
            unsigned hh = ((i0 + cx) * 1u) ^ ((i1 + cy) * 2654435761u) ^ ((i2 + cz) * 805459861u);
            hh &= 65535u;
            float wt = (cx ? w0 : 1.0f - w0) * (cy ? w1 : 1.0f - w1) * (cz ? w2 : 1.0f - w2);
            const float4 tv = *reinterpret_cast<const float4*>(tables + ((size_t)l*TBL + hh)*4);
            a0 = fmaf(tv.x, wt, a0); a1 = fmaf(tv.y, wt, a1);
            a2 = fmaf(tv.z, wt, a2); a3 = fmaf(tv.w, wt, a3);
        }
        float sc = erff(rsqrtf(8.0f*(float)l*crf + 1e-12f));
        h0[l*4+0] = a0*sc; h0[l*4+1] = a1*sc; h0[l*4+2] = a2*sc; h0[l*4+3] = a3*sc;
        res *= 2.0f;
    }

    float h1[NHID];
    #pragma unroll
    for (int j = 0; j < NHID; ++j) h1[j] = b1[j];
    #pragma unroll
    for (int i = 0; i < NIN; ++i) {
        float hi = h0[i];
        #pragma unroll
        for (int j = 0; j < NHID; ++j) h1[j] = fmaf(hi, W1[i*NHID + j], h1[j]);
    }
    #pragma unroll
    for (int j = 0; j < NHID; ++j) h1[j] = selu_f(h1[j]);

    float o[13];
    #pragma unroll
    for (int k = 0; k < 13; ++k) o[k] = b3[k];
    #pragma unroll
    for (int half = 0; half < 2; ++half) {
        float h2h[32];
        #pragma unroll
        for (int jj = 0; jj < 32; ++jj) h2h[jj] = b2[half*32 + jj];
        #pragma unroll
        for (int i = 0; i < NHID; ++i) {
            float hi = h1[i];
            #pragma unroll
            for (int jj = 0; jj < 32; ++jj)
                h2h[jj] = fmaf(hi, W2[i*NHID + half*32 + jj], h2h[jj]);
        }
        #pragma unroll
        for (int jj = 0; jj < 32; ++jj) {
            float hv = selu_f(h2h[jj]);
            #pragma unroll
            for (int k = 0; k < 13; ++k)
                o[k] = fmaf(hv, W3[(half*32 + jj)*13 + k], o[k]);
        }
    }

    float dv = fminf(fmaxf(o[0] - 1.0f, -30.0f), 10.0f);
    float density = __expf(dv);
    float el = 0.0f;
    #pragma unroll
    for (int a = 0; a < 3; ++a)
        #pragma unroll
        for (int bq = a+1; bq < 4; ++bq) {
            float ddx = (float)(p[a][0]-p[bq][0]);
            float ddy = (float)(p[a][1]-p[bq][1]);
            float ddz = (float)(p[a][2]-p[bq][2]);
            el = fmaxf(el, sqrtf(ddx*ddx + ddy*ddy + ddz*ddz));
        }
    float alpha = 1.0f - __expf(-density * el);
    int ab = __float_as_int(alpha);
    atomicMax((int*)out + vv[0], ab);
    atomicMax((int*)out + vv[1], ab);
    atomicMax((int*)out + vv[2], ab);
    atomicMax((int*)out + vv[3], ab);

    float base0 = o[1] + 0.5f, base1 = o[2] + 0.5f, base2 = o[3] + 0.5f;
    float bc0 = fmaxf(base0, 0.0f), bc1 = fmaxf(base1, 0.0f), bc2 = fmaxf(base2, 0.0f);
    float g00 = bc0*fast_tanh(o[4]),  g01 = bc0*fast_tanh(o[5]),  g02 = bc0*fast_tanh(o[6]);
    float g10 = bc1*fast_tanh(o[7]),  g11 = bc1*fast_tanh(o[8]),  g12 = bc1*fast_tanh(o[9]);
    float g20 = bc2*fast_tanh(o[10]), g21 = bc2*fast_tanh(o[11]), g22 = bc2*fast_tanh(o[12]);

    float* vout = out + V + (size_t)t * 12;
    #pragma unroll
    for (int v = 0; v < 4; ++v) {
        float ox = (float)(p[v][0]-cc[0]), oy = (float)(p[v][1]-cc[1]), oz = (float)(p[v][2]-cc[2]);
        float inv = rsqrtf(ox*ox + oy*oy + oz*oz + 1e-8f);
        float q0 = ox*inv, q1 = oy*inv, q2 = oz*inv;
        vout[v*3+0] = base0 + g00*q0 + g01*q1 + g02*q2;
        vout[v*3+1] = base1 + g10*q0 + g11*q1 + g12*q2;
        vout[v*3+2] = base2 + g20*q0 + g21*q1 + g22*q2;
    }
}

extern "C" void kernel_launch(void* const* d_in, const int* in_sizes, int n_in,
                              void* d_out, int out_size, void* d_ws, size_t ws_size,
                              hipStream_t stream) {
    const float* vertices = (const float*)d_in[0];
    const int*   indices  = (const int*)d_in[1];
    const float* center   = (const float*)d_in[2];
    const float* tables   = (const float*)d_in[3];
    const float* W1 = (const float*)d_in[4];
    const float* b1 = (const float*)d_in[5];
    const float* W2 = (const float*)d_in[6];
    const float* b2 = (const float*)d_in[7];
    const float* W3 = (const float*)d_in[8];
    const float* b3 = (const float*)d_in[9];
    int V = in_sizes[0] / 3;
    int T = in_sizes[1] / 4;
    float* out = (float*)d_out;

    hipLaunchKernelGGL(zero_alpha_kernel, dim3((V + 255) / 256), dim3(256), 0, stream, out, V);

    // ws: aux f32[8][T] (32B/tet) + feats_hi u16[T][40] (80B/tet) + feats_lo (80B/tet)
    size_t need = (size_t)T * 48 * sizeof(float);
    dim3 grid((T + 255) / 256), blk(256);
    if (ws_size >= need) {
        float* aux = (float*)d_ws;
        ushort* feats_hi = (ushort*)(aux + (size_t)T * 8);
        ushort* feats_lo = feats_hi + (size_t)T * NIN;
        hipLaunchKernelGGL(geom01_kernel, grid, blk, 0, stream,
                           vertices, indices, center, tables, aux, feats_hi, feats_lo, T);
        hipLaunchKernelGGL((hash_pass_kernel<2>), grid, blk, 0, stream, tables, aux, feats_hi, feats_lo, T);
        hipLaunchKernelGGL((hash_pass_kernel<4>), grid, blk, 0, stream, tables, aux, feats_hi, feats_lo, T);
        hipLaunchKernelGGL((hash_pass_kernel<6>), grid, blk, 0, stream, tables, aux, feats_hi, feats_lo, T);
        hipLaunchKernelGGL((hash_pass_kernel<8>), grid, blk, 0, stream, tables, aux, feats_hi, feats_lo, T);
        hipLaunchKernelGGL(mlp_mfma_kernel, dim3(768), blk, 0, stream, feats_hi, feats_lo, aux,
                           vertices, indices, W1, b1, W2, b2, W3, b3, out, T, V);
    } else {
        hipLaunchKernelGGL(tet_forward_fused, grid, blk, 0, stream,
                           vertices, indices, center, tables, W1, b1, W2, b2, W3, b3, out, T, V);
    }
}

// Round 18
// 228.553 us; speedup vs baseline: 1.0383x; 1.0084x over previous
//
#include <hip/hip_runtime.h>
#include <math.h>

#define NLVL 10
#define TBL 65536
#define NHID 64
#define NIN 40
#define LDP 68   // padded LDS row stride (floats)

typedef __attribute__((ext_vector_type(8))) short bf16x8;
typedef __attribute__((ext_vector_type(4))) float f32x4;
typedef unsigned int uint;
typedef unsigned short ushort;

__device__ __forceinline__ float selu_f(float x) {
    return 1.0507009873554805f * (x > 0.0f ? x : 1.6732632423543772f * (__expf(x) - 1.0f));
}
__device__ __forceinline__ float fast_tanh(float x) {
    float xx = fminf(fmaxf(x, -15.0f), 15.0f);
    float t = __expf(2.0f * xx);
    return (t - 1.0f) / (t + 1.0f);
}
// round-nearest f32 -> bf16 bits
__device__ __forceinline__ unsigned short f2bf(float x) {
    unsigned u = __float_as_uint(x);
    unsigned r = (u + 0x7FFFu + ((u >> 16) & 1u)) >> 16;
    return (unsigned short)r;
}
// truncation split: hi = top16 bits, lo = bf16-trunc of residual.
__device__ __forceinline__ short2 tsplit(float x) {
    uint u = __float_as_uint(x);
    short hi = (short)(u >> 16);
    float hif = __uint_as_float(u & 0xFFFF0000u);
    float lo = x - hif;
    short los = (short)(__float_as_uint(lo) >> 16);
    short2 s; s.x = hi; s.y = los;
    return s;
}

// Solve A x = b for 3x3 A (double precision, adjugate/Cramer).
__device__ __forceinline__ void solve3d(const double A[3][3], const double b[3], double x[3]) {
    double a00=A[0][0], a01=A[0][1], a02=A[0][2];
    double a10=A[1][0], a11=A[1][1], a12=A[1][2];
    double a20=A[2][0], a21=A[2][1], a22=A[2][2];
    double C00 =  (a11*a22 - a12*a21);
    double C01 = -(a10*a22 - a12*a20);
    double C02 =  (a10*a21 - a11*a20);
    double C10 = -(a01*a22 - a02*a21);
    double C11 =  (a00*a22 - a02*a20);
    double C12 = -(a00*a21 - a01*a20);
    double C20 =  (a01*a12 - a02*a11);
    double C21 = -(a00*a12 - a02*a10);
    double C22 =  (a00*a11 - a01*a10);
    double det = a00*C00 + a01*C01 + a02*C02;
    double inv = 1.0 / det;
    x[0] = (C00*b[0] + C10*b[1] + C20*b[2]) * inv;
    x[1] = (C01*b[0] + C11*b[1] + C21*b[2]) * inv;
    x[2] = (C02*b[0] + C12*b[1] + C22*b[2]) * inv;
}

__global__ void __launch_bounds__(256) zero_alpha_kernel(float* out, int V) {
    int i = blockIdx.x * blockDim.x + threadIdx.x;
    if (i < V) out[i] = 0.0f;
}

// Encode 2 consecutive levels (l0, l0+1) for one point.
__device__ __forceinline__ void enc2(const float4* __restrict__ tb4,
                                     float px, float py, float pz, float crf,
                                     int l0, float f[8]) {
    uint idx[2][8];
    float wt[2][8];
    #pragma unroll
    for (int h = 0; h < 2; ++h) {
        int l = l0 + h;
        float res = (float)(16 << l);
        float x0 = px*res, x1 = py*res, x2 = pz*res;
        float f0 = floorf(x0), f1 = floorf(x1), f2 = floorf(x2);
        float w0 = x0-f0, w1 = x1-f1, w2 = x2-f2;
        uint i0 = (uint)f0, i1 = (uint)f1, i2 = (uint)f2;
        #pragma unroll
        for (int cn = 0; cn < 8; ++cn) {
            uint cx = (uint)(cn & 1), cy = (uint)((cn >> 1) & 1), cz = (uint)((cn >> 2) & 1);
            idx[h][cn] = (((i0 + cx) * 1u) ^ ((i1 + cy) * 2654435761u) ^ ((i2 + cz) * 805459861u)) & 65535u;
            wt[h][cn] = (cx ? w0 : 1.0f - w0) * (cy ? w1 : 1.0f - w1) * (cz ? w2 : 1.0f - w2);
        }
    }
    float4 v[2][8];
    #pragma unroll
    for (int h = 0; h < 2; ++h)
        #pragma unroll
        for (int cn = 0; cn < 8; ++cn)
            v[h][cn] = tb4[(size_t)(l0+h)*TBL + idx[h][cn]];
    #pragma unroll
    for (int h = 0; h < 2; ++h) {
        float a0=0.f, a1=0.f, a2=0.f, a3=0.f;
        #pragma unroll
        for (int cn = 0; cn < 8; ++cn) {
            float w = wt[h][cn];
            a0 = fmaf(v[h][cn].x, w, a0);
            a1 = fmaf(v[h][cn].y, w, a1);
            a2 = fmaf(v[h][cn].z, w, a2);
            a3 = fmaf(v[h][cn].w, w, a3);
        }
        float sc = erff(rsqrtf(8.0f*(float)(l0+h)*crf + 1e-12f));
        f[h*4+0] = a0*sc; f[h*4+1] = a1*sc; f[h*4+2] = a2*sc; f[h*4+3] = a3*sc;
    }
}

// split f[8] into bf16 hi/lo planes and store as two 16B vectors
__device__ __forceinline__ void store_split8(const float f[8],
                                             ushort* __restrict__ fh,
                                             ushort* __restrict__ fl) {
    bf16x8 h8, l8;
    #pragma unroll
    for (int j = 0; j < 8; ++j) {
        short2 sp = tsplit(f[j]);
        h8[j] = sp.x; l8[j] = sp.y;
    }
    *reinterpret_cast<bf16x8*>(fh) = h8;
    *reinterpret_cast<bf16x8*>(fl) = l8;
}

// ---------------- Kernel 1: geometry + hash levels 0,1 ----------------
__global__ void __launch_bounds__(256) geom01_kernel(
    const float* __restrict__ vertices,
    const int*   __restrict__ indices,
    const float* __restrict__ center,
    const float* __restrict__ tables,
    float* __restrict__ aux,
    ushort* __restrict__ feats_hi,
    ushort* __restrict__ feats_lo, int T)
{
    int t = blockIdx.x * blockDim.x + threadIdx.x;
    if (t >= T) return;

    double p[4][3];
    #pragma unroll
    for (int v = 0; v < 4; ++v) {
        int vid = indices[t*4+v];
        p[v][0] = (double)vertices[vid*3+0];
        p[v][1] = (double)vertices[vid*3+1];
        p[v][2] = (double)vertices[vid*3+2];
    }

    double A[3][3], bb[3];
    double v0sq = p[0][0]*p[0][0] + p[0][1]*p[0][1] + p[0][2]*p[0][2];
    #pragma unroll
    for (int i = 0; i < 3; ++i) {
        #pragma unroll
        for (int j = 0; j < 3; ++j)
            A[i][j] = 2.0*(p[i+1][j] - p[0][j]) + (i==j ? 1e-6 : 0.0);
        bb[i] = p[i+1][0]*p[i+1][0] + p[i+1][1]*p[i+1][1] + p[i+1][2]*p[i+1][2] - v0sq;
    }
    double c[3];
    solve3d(A, bb, c);
    double dx0 = c[0]-p[0][0], dy0 = c[1]-p[0][1], dz0 = c[2]-p[0][2];
    double radius = sqrt(dx0*dx0 + dy0*dy0 + dz0*dz0);

    double E[3][3];
    #pragma unroll
    for (int i = 0; i < 3; ++i)
        #pragma unroll
        for (int j = 0; j < 3; ++j)
            E[i][j] = p[i+1][j] - p[0][j];
    double M[3][3], rhs[3];
    #pragma unroll
    for (int i = 0; i < 3; ++i) {
        #pragma unroll
        for (int k = 0; k < 3; ++k)
            M[i][k] = E[i][0]*E[k][0] + E[i][1]*E[k][1] + E[i][2]*E[k][2] + (i==k ? 1e-6 : 0.0);
        rhs[i] = E[i][0]*dx0 + E[i][1]*dy0 + E[i][2]*dz0;
    }
    double lam[3];
    solve3d(M, rhs, lam);
    double bary[4];
    bary[0] = 1.0 - lam[0] - lam[1] - lam[2];
    bary[1] = lam[0]; bary[2] = lam[1]; bary[3] = lam[2];
    double bs = 0.0;
    #pragma unroll
    for (int v = 0; v < 4; ++v) {
        bary[v] = fmin(fmax(bary[v], 0.0), 1.0);
        bs += bary[v];
    }
    bs = fmax(bs, 1e-6);
    double cc[3];
    #pragma unroll
    for (int j = 0; j < 3; ++j)
        cc[j] = (bary[0]*p[0][j] + bary[1]*p[1][j] + bary[2]*p[2][j] + bary[3]*p[3][j]) / bs;

    double xv[3];
    xv[0] = (cc[0] - (double)center[0]) * 0.5;
    xv[1] = (cc[1] - (double)center[1]) * 0.5;
    xv[2] = (cc[2] - (double)center[2]) * 0.5;
    double nrm = sqrt(xv[0]*xv[0] + xv[1]*xv[1] + xv[2]*xv[2]);
    double n = fmax(nrm, 1e-9);
    double cv[3], cs;
    if (n <= 1.0) {
        cv[0]=xv[0]; cv[1]=xv[1]; cv[2]=xv[2];
        cs = radius * 0.5;
    } else {
        double f = (2.0 - 1.0/n) / n;
        cv[0]=xv[0]*f; cv[1]=xv[1]*f; cv[2]=xv[2]*f;
        cs = radius * 0.5 / (n*n);
    }
    float crf = (float)(cs * 0.5);  // SCALE_MULTI

    float px = fminf(fmaxf((float)(cv[0]*0.25 + 0.5), 0.0f), 1.0f - 1e-6f);
    float py = fminf(fmaxf((float)(cv[1]*0.25 + 0.5), 0.0f), 1.0f - 1e-6f);
    float pz = fminf(fmaxf((float)(cv[2]*0.25 + 0.5), 0.0f), 1.0f - 1e-6f);

    float el = 0.0f;
    #pragma unroll
    for (int a = 0; a < 3; ++a)
        #pragma unroll
        for (int bq = a+1; bq < 4; ++bq) {
            float ddx = (float)(p[a][0]-p[bq][0]);
            float ddy = (float)(p[a][1]-p[bq][1]);
            float ddz = (float)(p[a][2]-p[bq][2]);
            el = fmaxf(el, sqrtf(ddx*ddx + ddy*ddy + ddz*ddz));
        }

    size_t st = (size_t)T;
    aux[0*st + t] = px;
    aux[1*st + t] = py;
    aux[2*st + t] = pz;
    aux[3*st + t] = crf;
    aux[4*st + t] = (float)cc[0];
    aux[5*st + t] = (float)cc[1];
    aux[6*st + t] = (float)cc[2];
    aux[7*st + t] = el;

    const float4* tb4 = reinterpret_cast<const float4*>(tables);
    float f01[8];
    enc2(tb4, px, py, pz, crf, 0, f01);
    store_split8(f01, feats_hi + (size_t)t*NIN, feats_lo + (size_t)t*NIN);
}

// ---------------- Kernel 2 (x4): hash levels (L0, L0+1) ----------------
template<int L0>
__global__ void __launch_bounds__(256) hash_pass_kernel(
    const float* __restrict__ tables,
    const float* __restrict__ aux,
    ushort* __restrict__ feats_hi,
    ushort* __restrict__ feats_lo, int T)
{
    int t = blockIdx.x * blockDim.x + threadIdx.x;
    if (t >= T) return;
    size_t st = (size_t)T;
    float px = aux[0*st + t];
    float py = aux[1*st + t];
    float pz = aux[2*st + t];
    float crf = aux[3*st + t];
    const float4* tb4 = reinterpret_cast<const float4*>(tables);

    float f[8];
    enc2(tb4, px, py, pz, crf, L0, f);
    store_split8(f, feats_hi + (size_t)t*NIN + L0*4, feats_lo + (size_t)t*NIN + L0*4);
}

// ---------------- Kernel 3: MFMA MLP + epilogue (weights in LDS, pure bf16-rn) ----------------
// All weights round-nearest bf16 (single plane). Precision headroom justified:
// absmax has been pinned at 0.00586 since the all-fp32 round-0 kernel, so MLP
// precision is not the error floor. LDS 35.8KB -> 4 blocks/CU.
__global__ void __launch_bounds__(256, 4) mlp_mfma_kernel(
    const ushort* __restrict__ feats_hi,
    const ushort* __restrict__ feats_lo,
    const float* __restrict__ aux,
    const float* __restrict__ vertices,
    const int*   __restrict__ indices,
    const float* __restrict__ W1, const float* __restrict__ b1,
    const float* __restrict__ W2, const float* __restrict__ b2,
    const float* __restrict__ W3, const float* __restrict__ b3,
    float* __restrict__ out, int T, int V)
{
    __shared__ __align__(16) float hts[4][16][LDP];   // 17.4 KB
    __shared__ bf16x8 sW1[8*64];   // 8 KB  [ (s*4+nt)*64 + lane ]
    __shared__ bf16x8 sW2[8*64];   // 8 KB
    __shared__ bf16x8 sW3[2*64];   // 2 KB

    const int tid  = threadIdx.x;
    const int wid  = tid >> 6;
    const int lane = tid & 63;
    const int r    = lane & 15;
    const int g    = lane >> 4;

    // ---- cooperative weight staging (once per block), round-nearest bf16 ----
    for (int slot = tid; slot < 8*64; slot += 256) {
        int set = slot >> 6, l = slot & 63;
        int s = set >> 2, nt = set & 3;
        int rr = l & 15, gg = l >> 4;
        bf16x8 h;
        #pragma unroll
        for (int j = 0; j < 8; ++j) {
            int k = s*32 + gg*8 + j;
            float w = (k < NIN) ? W1[k*NHID + nt*16 + rr] : 0.0f;
            h[j] = (short)f2bf(w);
        }
        sW1[slot] = h;
    }
    for (int slot = tid; slot < 8*64; slot += 256) {
        int set = slot >> 6, l = slot & 63;
        int s = set >> 2, nt = set & 3;
        int rr = l & 15, gg = l >> 4;
        bf16x8 h;
        #pragma unroll
        for (int j = 0; j < 8; ++j) {
            int k = s*32 + gg*8 + j;
            h[j] = (short)f2bf(W2[k*NHID + nt*16 + rr]);
        }
        sW2[slot] = h;
    }
    for (int slot = tid; slot < 2*64; slot += 256) {
        int s = slot >> 6, l = slot & 63;
        int rr = l & 15, gg = l >> 4;
        bf16x8 h;
        #pragma unroll
        for (int j = 0; j < 8; ++j) {
            int k = s*32 + gg*8 + j;
            float w = (rr < 13) ? W3[k*13 + rr] : 0.0f;
            h[j] = (short)f2bf(w);
        }
        sW3[slot] = h;
    }
    __syncthreads();

    float b1v[4], b2v[4];
    #pragma unroll
    for (int nt = 0; nt < 4; ++nt) { b1v[nt] = b1[nt*16 + r]; b2v[nt] = b2[nt*16 + r]; }
    float b3v = (r < 13) ? b3[r] : 0.0f;

    const size_t st = (size_t)T;
    const int nmt = (T + 15) >> 4;
    const int gw = blockIdx.x * 4 + wid;
    const int gstride = gridDim.x * 4;
    const bf16x8 zfrag = {0,0,0,0,0,0,0,0};

    if (gw >= nmt) return;

    // ---- preload A-frags for first tile ----
    bf16x8 ah0, al0, ah1;
    {
        int trow = gw*16 + r;
        bool rowok = trow < T;
        const ushort* fh = feats_hi + (size_t)trow * NIN;
        const ushort* fl = feats_lo + (size_t)trow * NIN;
        ah0 = rowok ? *reinterpret_cast<const bf16x8*>(fh + g*8) : zfrag;
        al0 = rowok ? *reinterpret_cast<const bf16x8*>(fl + g*8) : zfrag;
        ah1 = (rowok && g == 0) ? *reinterpret_cast<const bf16x8*>(fh + 32) : zfrag;
    }

    for (int mt = gw; mt < nmt; mt += gstride) {
        const int t0 = mt * 16;

        // ---- prefetch epilogue inputs for THIS tile ----
        const int te = t0 + (lane >> 2);
        const int ev = lane & 3;
        const bool teok = te < T;
        int vid = teok ? indices[te*4 + ev] : 0;
        float el  = teok ? aux[7*st + te] : 0.0f;
        float cc0 = teok ? aux[4*st + te] : 0.0f;
        float cc1 = teok ? aux[5*st + te] : 0.0f;
        float cc2 = teok ? aux[6*st + te] : 0.0f;

        // ---- layer 1 MFMA (12 ops) ----
        __builtin_amdgcn_s_setprio(1);
        #pragma unroll
        for (int nt = 0; nt < 4; ++nt) {
            f32x4 acc = {0.f, 0.f, 0.f, 0.f};
            acc = __builtin_amdgcn_mfma_f32_16x16x32_bf16(ah0, sW1[nt*64 + lane],     acc, 0, 0, 0);
            acc = __builtin_amdgcn_mfma_f32_16x16x32_bf16(al0, sW1[nt*64 + lane],     acc, 0, 0, 0);
            acc = __builtin_amdgcn_mfma_f32_16x16x32_bf16(ah1, sW1[(4+nt)*64 + lane], acc, 0, 0, 0);
            #pragma unroll
            for (int q = 0; q < 4; ++q)
                hts[wid][g*4 + q][nt*16 + r] = selu_f(acc[q] + b1v[nt]);
        }
        __builtin_amdgcn_s_setprio(0);

        // ---- issue next tile's A-frag loads ----
        const int mtn = mt + gstride;
        bf16x8 nah0 = zfrag, nal0 = zfrag, nah1 = zfrag;
        if (mtn < nmt) {
            int trow = mtn*16 + r;
            bool rowok = trow < T;
            const ushort* fh = feats_hi + (size_t)trow * NIN;
            const ushort* fl = feats_lo + (size_t)trow * NIN;
            if (rowok) {
                nah0 = *reinterpret_cast<const bf16x8*>(fh + g*8);
                nal0 = *reinterpret_cast<const bf16x8*>(fl + g*8);
                if (g == 0) nah1 = *reinterpret_cast<const bf16x8*>(fh + 32);
            }
        }

        // ---- dependent vertex loads ----
        float pvx = vertices[vid*3+0];
        float pvy = vertices[vid*3+1];
        float pvz = vertices[vid*3+2];

        asm volatile("s_waitcnt lgkmcnt(0)" ::: "memory");

        // ---- layer 2: A-frags from LDS, round-nearest bf16 ----
        bf16x8 a2[2];
        #pragma unroll
        for (int s = 0; s < 2; ++s) {
            float4 u0 = *reinterpret_cast<const float4*>(&hts[wid][r][s*32 + g*8]);
            float4 u1 = *reinterpret_cast<const float4*>(&hts[wid][r][s*32 + g*8 + 4]);
            bf16x8 h;
            h[0] = (short)f2bf(u0.x); h[1] = (short)f2bf(u0.y);
            h[2] = (short)f2bf(u0.z); h[3] = (short)f2bf(u0.w);
            h[4] = (short)f2bf(u1.x); h[5] = (short)f2bf(u1.y);
            h[6] = (short)f2bf(u1.z); h[7] = (short)f2bf(u1.w);
            a2[s] = h;
        }
        asm volatile("s_waitcnt lgkmcnt(0)" ::: "memory");
        float h2v[4][4];
        __builtin_amdgcn_s_setprio(1);
        #pragma unroll
        for (int nt = 0; nt < 4; ++nt) {
            f32x4 acc = {0.f, 0.f, 0.f, 0.f};
            #pragma unroll
            for (int s = 0; s < 2; ++s)
                acc = __builtin_amdgcn_mfma_f32_16x16x32_bf16(a2[s], sW2[(s*4+nt)*64 + lane], acc, 0, 0, 0);
            #pragma unroll
            for (int q = 0; q < 4; ++q) h2v[nt][q] = selu_f(acc[q] + b2v[nt]);
        }
        __builtin_amdgcn_s_setprio(0);
        #pragma unroll
        for (int nt = 0; nt < 4; ++nt)
            #pragma unroll
            for (int q = 0; q < 4; ++q)
                hts[wid][g*4 + q][nt*16 + r] = h2v[nt][q];
        asm volatile("s_waitcnt lgkmcnt(0)" ::: "memory");

        // ---- layer 3: A-frags from LDS, round-nearest bf16 ----
        bf16x8 a3[2];
        #pragma unroll
        for (int s = 0; s < 2; ++s) {
            float4 u0 = *reinterpret_cast<const float4*>(&hts[wid][r][s*32 + g*8]);
            float4 u1 = *reinterpret_cast<const float4*>(&hts[wid][r][s*32 + g*8 + 4]);
            bf16x8 h;
            h[0] = (short)f2bf(u0.x); h[1] = (short)f2bf(u0.y);
            h[2] = (short)f2bf(u0.z); h[3] = (short)f2bf(u0.w);
            h[4] = (short)f2bf(u1.x); h[5] = (short)f2bf(u1.y);
            h[6] = (short)f2bf(u1.z); h[7] = (short)f2bf(u1.w);
            a3[s] = h;
        }
        asm volatile("s_waitcnt lgkmcnt(0)" ::: "memory");
        {
            f32x4 acc = {0.f, 0.f, 0.f, 0.f};
            __builtin_amdgcn_s_setprio(1);
            #pragma unroll
            for (int s = 0; s < 2; ++s)
                acc = __builtin_amdgcn_mfma_f32_16x16x32_bf16(a3[s], sW3[s*64 + lane], acc, 0, 0, 0);
            __builtin_amdgcn_s_setprio(0);
            #pragma unroll
            for (int q = 0; q < 4; ++q)
                hts[wid][g*4 + q][r] = acc[q] + b3v;
        }
        asm volatile("s_waitcnt lgkmcnt(0)" ::: "memory");

        // ---- epilogue: one (tet, vertex) per lane ----
        if (teok) {
            const float* orow = hts[wid][lane >> 2];
            float4 o0 = *reinterpret_cast<const float4*>(&orow[0]);
            float4 o1 = *reinterpret_cast<const float4*>(&orow[4]);
            float4 o2 = *reinterpret_cast<const float4*>(&orow[8]);
            float o12 = orow[12];

            float dv = fminf(fmaxf(o0.x - 1.0f, -30.0f), 10.0f);
            float density = __expf(dv);
            float alpha = 1.0f - __expf(-density * el);
            int ab = __float_as_int(alpha);
            atomicMax((int*)out + vid, ab);

            float base0 = o0.y + 0.5f, base1 = o0.z + 0.5f, base2 = o0.w + 0.5f;
            float bc0 = fmaxf(base0, 0.0f), bc1 = fmaxf(base1, 0.0f), bc2 = fmaxf(base2, 0.0f);
            float g00 = bc0*fast_tanh(o1.x), g01 = bc0*fast_tanh(o1.y), g02 = bc0*fast_tanh(o1.z);
            float g10 = bc1*fast_tanh(o1.w), g11 = bc1*fast_tanh(o2.x), g12 = bc1*fast_tanh(o2.y);
            float g20 = bc2*fast_tanh(o2.z), g21 = bc2*fast_tanh(o2.w), g22 = bc2*fast_tanh(o12);

            float ox = pvx-cc0, oy = pvy-cc1, oz = pvz-cc2;
            float inv = rsqrtf(ox*ox + oy*oy + oz*oz + 1e-8f);
            float q0 = ox*inv, q1 = oy*inv, q2 = oz*inv;
            float* vout = out + V + (size_t)te * 12 + ev*3;
            vout[0] = base0 + g00*q0 + g01*q1 + g02*q2;
            vout[1] = base1 + g10*q0 + g11*q1 + g12*q2;
            vout[2] = base2 + g20*q0 + g21*q1 + g22*q2;
        }
        asm volatile("s_waitcnt lgkmcnt(0)" ::: "memory");

        ah0 = nah0; al0 = nal0; ah1 = nah1;
    }
}

// ---------------- Fallback fused kernel (used only if ws is too small) ----------------
__global__ void __launch_bounds__(256) tet_forward_fused(
    const float* __restrict__ vertices,
    const int*   __restrict__ indices,
    const float* __restrict__ center,
    const float* __restrict__ tables,
    const float* __restrict__ W1, const float* __restrict__ b1,
    const float* __restrict__ W2, const float* __restrict__ b2,
    const float* __restrict__ W3, const float* __restrict__ b3,
    float* __restrict__ out, int T, int V)
{
    int t = blockIdx.x * blockDim.x + threadIdx.x;
    if (t >= T) return;

    double p[4][3];
    int vv[4];
    #pragma unroll
    for (int v = 0; v < 4; ++v) {
        vv[v] = indices[t*4+v];
        p[v][0] = (double)vertices[vv[v]*3+0];
        p[v][1] = (double)vertices[vv[v]*3+1];
        p[v][2] = (double)vertices[vv[v]*3+2];
    }
    double A[3][3], bb[3];
    double v0sq = p[0][0]*p[0][0] + p[0][1]*p[0][1] + p[0][2]*p[0][2];
    #pragma unroll
    for (int i = 0; i < 3; ++i) {
        #pragma unroll
        for (int j = 0; j < 3; ++j)
            A[i][j] = 2.0*(p[i+1][j] - p[0][j]) + (i==j ? 1e-6 : 0.0);
        bb[i] = p[i+1][0]*p[i+1][0] + p[i+1][1]*p[i+1][1] + p[i+1][2]*p[i+1][2] - v0sq;
    }
    double c[3];
    solve3d(A, bb, c);
    double dx0 = c[0]-p[0][0], dy0 = c[1]-p[0][1], dz0 = c[2]-p[0][2];
    double radius = sqrt(dx0*dx0 + dy0*dy0 + dz0*dz0);
    double E[3][3];
    #pragma unroll
    for (int i = 0; i < 3; ++i)
        #pragma unroll
        for (int j = 0; j < 3; ++j)
            E[i][j] = p[i+1][j] - p[0][j];
    double M[3][3], rhs[3];
    #pragma unroll
    for (int i = 0; i < 3; ++i) {
        #pragma unroll
        for (int k = 0; k < 3; ++k)
            M[i][k] = E[i][0]*E[k][0] + E[i][1]*E[k][1] + E[i][2]*E[k][2] + (i==k ? 1e-6 : 0.0);
        rhs[i] = E[i][0]*dx0 + E[i][1]*dy0 + E[i][2]*dz0;
    }
    double lam[3];
    solve3d(M, rhs, lam);
    double bary[4];
    bary[0] = 1.0 - lam[0] - lam[1] - lam[2];
    bary[1] = lam[0]; bary[2] = lam[1]; bary[3] = lam[2];
    double bs = 0.0;
    #pragma unroll
    for (int v = 0; v < 4; ++v) { bary[v] = fmin(fmax(bary[v], 0.0), 1.0); bs += bary[v]; }
    bs = fmax(bs, 1e-6);
    double cc[3];
    #pragma unroll
    for (int j = 0; j < 3; ++j)
        cc[j] = (bary[0]*p[0][j] + bary[1]*p[1][j] + bary[2]*p[2][j] + bary[3]*p[3][j]) / bs;
    double xv[3];
    xv[0] = (cc[0] - (double)center[0]) * 0.5;
    xv[1] = (cc[1] - (double)center[1]) * 0.5;
    xv[2] = (cc[2] - (double)center[2]) * 0.5;
    double nrm = sqrt(xv[0]*xv[0] + xv[1]*xv[1] + xv[2]*xv[2]);
    double n = fmax(nrm, 1e-9);
    double cv[3], cs;
    if (n <= 1.0) { cv[0]=xv[0]; cv[1]=xv[1]; cv[2]=xv[2]; cs = radius * 0.5; }
    else { double f = (2.0 - 1.0/n) / n; cv[0]=xv[0]*f; cv[1]=xv[1]*f; cv[2]=xv[2]*f; cs = radius * 0.5 / (n*n); }
    float crf = (float)(cs * 0.5);
    float pos0 = fminf(fmaxf((float)(cv[0]*0.25 + 0.5), 0.0f), 1.0f - 1e-6f);
    float pos1 = fminf(fmaxf((float)(cv[1]*0.25 + 0.5), 0.0f), 1.0f - 1e-6f);
    float pos2 = fminf(fmaxf((float)(cv[2]*0.25 + 0.5), 0.0f), 1.0f - 1e-6f);

    float h0[NIN];
    float res = 16.0f;
    #pragma unroll
    for (int l = 0; l < NLVL; ++l) {
        float x0 = pos0*res, x1 = pos1*res, x2 = pos2*res;
        float f0 = floorf(x0), f1 = floorf(x1), f2 = floorf(x2);
        float w0 = x0-f0, w1 = x1-f1, w2 = x2-f2;
        unsigned i0 = (unsigned)f0, i1 = (unsigned)f1, i2 = (unsigned)f2;
        float a0=0.f, a1=0.f, a2=0.f, a3=0.f;
        #pragma unroll
        for (int cn = 0; cn < 8; ++cn) {
            unsigned cx = (unsigned)(cn & 1), cy = (unsigned)((cn >> 1) & 1), cz = (unsigned)((cn >> 2) & 1);
            unsigned hh = ((i0 + cx) * 1u) ^ ((i1 + cy) * 2654435761u) ^ ((i2 + cz) * 805459861u);
            hh &= 65535u;
            float wt = (cx ? w0 : 1.0f - w0) * (cy ? w1 : 1.0f - w1) * (cz ? w2 : 1.0f - w2);
            const float4 tv = *reinterpret_cast<const float4*>(tables + ((size_t)l*TBL + hh)*4);
            a0 = fmaf(tv.x, wt, a0); a1 = fmaf(tv.y, wt, a1);
            a2 = fmaf(tv.z, wt, a2); a3 = fmaf(tv.w, wt, a3);
        }
        float sc = erff(rsqrtf(8.0f*(float)l*crf + 1e-12f));
        h0[l*4+0] = a0*sc; h0[l*4+1] = a1*sc; h0[l*4+2] = a2*sc; h0[l*4+3] = a3*sc;
        res *= 2.0f;
    }

    float h1[NHID];
    #pragma unroll
    for (int j = 0; j < NHID; ++j) h1[j] = b1[j];
    #pragma unroll
    for (int i = 0; i < NIN; ++i) {
        float hi = h0[i];
        #pragma unroll
        for (int j = 0; j < NHID; ++j) h1[j] = fmaf(hi, W1[i*NHID + j], h1[j]);
    }
    #pragma unroll
    for (int j = 0; j < NHID; ++j) h1[j] = selu_f(h1[j]);

    float o[13];
    #pragma unroll
    for (int k = 0; k < 13; ++k) o[k] = b3[k];
    #pragma unroll
    for (int half = 0; half < 2; ++half) {
        float h2h[32];
        #pragma unroll
        for (int jj = 0; jj < 32; ++jj) h2h[jj] = b2[half*32 + jj];
        #pragma unroll
        for (int i = 0; i < NHID; ++i) {
            float hi = h1[i];
            #pragma unroll
            for (int jj = 0; jj < 32; ++jj)
                h2h[jj] = fmaf(hi, W2[i*NHID + half*32 + jj], h2h[jj]);
        }
        #pragma unroll
        for (int jj = 0; jj < 32; ++jj) {
            float hv = selu_f(h2h[jj]);
            #pragma unroll
            for (int k = 0; k < 13; ++k)
                o[k] = fmaf(hv, W3[(half*32 + jj)*13 + k], o[k]);
        }
    }

    float dv = fminf(fmaxf(o[0] - 1.0f, -30.0f), 10.0f);
    float density = __expf(dv);
    float el = 0.0f;
    #pragma unroll
    for (int a = 0; a < 3; ++a)
        #pragma unroll
        for (int bq = a+1; bq < 4; ++bq) {
            float ddx = (float)(p[a][0]-p[bq][0]);
            float ddy = (float)(p[a][1]-p[bq][1]);
            float ddz = (float)(p[a][2]-p[bq][2]);
            el = fmaxf(el, sqrtf(ddx*ddx + ddy*ddy + ddz*ddz));
        }
    float alpha = 1.0f - __expf(-density * el);
    int ab = __float_as_int(alpha);
    atomicMax((int*)out + vv[0], ab);
    atomicMax((int*)out + vv[1], ab);
    atomicMax((int*)out + vv[2], ab);
    atomicMax((int*)out + vv[3], ab);

    float base0 = o[1] + 0.5f, base1 = o[2] + 0.5f, base2 = o[3] + 0.5f;
    float bc0 = fmaxf(base0, 0.0f), bc1 = fmaxf(base1, 0.0f), bc2 = fmaxf(base2, 0.0f);
    float g00 = bc0*fast_tanh(o[4]),  g01 = bc0*fast_tanh(o[5]),  g02 = bc0*fast_tanh(o[6]);
    float g10 = bc1*fast_tanh(o[7]),  g11 = bc1*fast_tanh(o[8]),  g12 = bc1*fast_tanh(o[9]);
    float g20 = bc2*fast_tanh(o[10]), g21 = bc2*fast_tanh(o[11]), g22 = bc2*fast_tanh(o[12]);

    float* vout = out + V + (size_t)t * 12;
    #pragma unroll
    for (int v = 0; v < 4; ++v) {
        float ox = (float)(p[v][0]-cc[0]), oy = (float)(p[v][1]-cc[1]), oz = (float)(p[v][2]-cc[2]);
        float inv = rsqrtf(ox*ox + oy*oy + oz*oz + 1e-8f);
        float q0 = ox*inv, q1 = oy*inv, q2 = oz*inv;
        vout[v*3+0] = base0 + g00*q0 + g01*q1 + g02*q2;
        vout[v*3+1] = base1 + g10*q0 + g11*q1 + g12*q2;
        vout[v*3+2] = base2 + g20*q0 + g21*q1 + g22*q2;
    }
}

extern "C" void kernel_launch(void* const* d_in, const int* in_sizes, int n_in,
                              void* d_out, int out_size, void* d_ws, size_t ws_size,
                              hipStream_t stream) {
    const float* vertices = (const float*)d_in[0];
    const int*   indices  = (const int*)d_in[1];
    const float* center   = (const float*)d_in[2];
    const float* tables   = (const float*)d_in[3];
    const float* W1 = (const float*)d_in[4];
    const float* b1 = (const float*)d_in[5];
    const float* W2 = (const float*)d_in[6];
    const float* b2 = (const float*)d_in[7];
    const float* W3 = (const float*)d_in[8];
    const float* b3 = (const float*)d_in[9];
    int V = in_sizes[0] / 3;
    int T = in_sizes[1] / 4;
    float* out = (float*)d_out;

    hipLaunchKernelGGL(zero_alpha_kernel, dim3((V + 255) / 256), dim3(256), 0, stream, out, V);

    // ws: aux f32[8][T] (32B/tet) + feats_hi u16[T][40] (80B/tet) + feats_lo (80B/tet)
    size_t need = (size_t)T * 48 * sizeof(float);
    dim3 grid((T + 255) / 256), blk(256);
    if (ws_size >= need) {
        float* aux = (float*)d_ws;
        ushort* feats_hi = (ushort*)(aux + (size_t)T * 8);
        ushort* feats_lo = feats_hi + (size_t)T * NIN;
        hipLaunchKernelGGL(geom01_kernel, grid, blk, 0, stream,
                           vertices, indices, center, tables, aux, feats_hi, feats_lo, T);
        hipLaunchKernelGGL((hash_pass_kernel<2>), grid, blk, 0, stream, tables, aux, feats_hi, feats_lo, T);
        hipLaunchKernelGGL((hash_pass_kernel<4>), grid, blk, 0, stream, tables, aux, feats_hi, feats_lo, T);
        hipLaunchKernelGGL((hash_pass_kernel<6>), grid, blk, 0, stream, tables, aux, feats_hi, feats_lo, T);
        hipLaunchKernelGGL((hash_pass_kernel<8>), grid, blk, 0, stream, tables, aux, feats_hi, feats_lo, T);
        hipLaunchKernelGGL(mlp_mfma_kernel, dim3(1024), blk, 0, stream, feats_hi, feats_lo, aux,
                           vertices, indices, W1, b1, W2, b2, W3, b3, out, T, V);
    } else {
        hipLaunchKernelGGL(tet_forward_fused, grid, blk, 0, stream,
                           vertices, indices, center, tables, W1, b1, W2, b2, W3, b3, out, T, V);
    }
}

// Round 19
// 219.786 us; speedup vs baseline: 1.0797x; 1.0399x over previous
//
#include <hip/hip_runtime.h>
#include <math.h>

#define NLVL 10
#define TBL 65536
#define NHID 64
#define NIN 40
#define LDP 68   // padded LDS row stride (floats)

typedef __attribute__((ext_vector_type(8))) short bf16x8;
typedef __attribute__((ext_vector_type(4))) float f32x4;
typedef unsigned int uint;
typedef unsigned short ushort;

__device__ __forceinline__ float selu_f(float x) {
    return 1.0507009873554805f * (x > 0.0f ? x : 1.6732632423543772f * (__expf(x) - 1.0f));
}
__device__ __forceinline__ float fast_tanh(float x) {
    float xx = fminf(fmaxf(x, -15.0f), 15.0f);
    float t = __expf(2.0f * xx);
    return (t - 1.0f) / (t + 1.0f);
}
// round-nearest f32 -> bf16 bits
__device__ __forceinline__ unsigned short f2bf(float x) {
    unsigned u = __float_as_uint(x);
    unsigned r = (u + 0x7FFFu + ((u >> 16) & 1u)) >> 16;
    return (unsigned short)r;
}
// truncation split: hi = top16 bits, lo = bf16-trunc of residual.
__device__ __forceinline__ short2 tsplit(float x) {
    uint u = __float_as_uint(x);
    short hi = (short)(u >> 16);
    float hif = __uint_as_float(u & 0xFFFF0000u);
    float lo = x - hif;
    short los = (short)(__float_as_uint(lo) >> 16);
    short2 s; s.x = hi; s.y = los;
    return s;
}

// Solve A x = b for 3x3 A (double precision, adjugate/Cramer).
__device__ __forceinline__ void solve3d(const double A[3][3], const double b[3], double x[3]) {
    double a00=A[0][0], a01=A[0][1], a02=A[0][2];
    double a10=A[1][0], a11=A[1][1], a12=A[1][2];
    double a20=A[2][0], a21=A[2][1], a22=A[2][2];
    double C00 =  (a11*a22 - a12*a21);
    double C01 = -(a10*a22 - a12*a20);
    double C02 =  (a10*a21 - a11*a20);
    double C10 = -(a01*a22 - a02*a21);
    double C11 =  (a00*a22 - a02*a20);
    double C12 = -(a00*a21 - a01*a20);
    double C20 =  (a01*a12 - a02*a11);
    double C21 = -(a00*a12 - a02*a10);
    double C22 =  (a00*a11 - a01*a10);
    double det = a00*C00 + a01*C01 + a02*C02;
    double inv = 1.0 / det;
    x[0] = (C00*b[0] + C10*b[1] + C20*b[2]) * inv;
    x[1] = (C01*b[0] + C11*b[1] + C21*b[2]) * inv;
    x[2] = (C02*b[0] + C12*b[1] + C22*b[2]) * inv;
}

// Encode 2 consecutive levels (l0, l0+1) for one point.
__device__ __forceinline__ void enc2(const float4* __restrict__ tb4,
                                     float px, float py, float pz, float crf,
                                     int l0, float f[8]) {
    uint idx[2][8];
    float wt[2][8];
    #pragma unroll
    for (int h = 0; h < 2; ++h) {
        int l = l0 + h;
        float res = (float)(16 << l);
        float x0 = px*res, x1 = py*res, x2 = pz*res;
        float f0 = floorf(x0), f1 = floorf(x1), f2 = floorf(x2);
        float w0 = x0-f0, w1 = x1-f1, w2 = x2-f2;
        uint i0 = (uint)f0, i1 = (uint)f1, i2 = (uint)f2;
        #pragma unroll
        for (int cn = 0; cn < 8; ++cn) {
            uint cx = (uint)(cn & 1), cy = (uint)((cn >> 1) & 1), cz = (uint)((cn >> 2) & 1);
            idx[h][cn] = (((i0 + cx) * 1u) ^ ((i1 + cy) * 2654435761u) ^ ((i2 + cz) * 805459861u)) & 65535u;
            wt[h][cn] = (cx ? w0 : 1.0f - w0) * (cy ? w1 : 1.0f - w1) * (cz ? w2 : 1.0f - w2);
        }
    }
    float4 v[2][8];
    #pragma unroll
    for (int h = 0; h < 2; ++h)
        #pragma unroll
        for (int cn = 0; cn < 8; ++cn)
            v[h][cn] = tb4[(size_t)(l0+h)*TBL + idx[h][cn]];
    #pragma unroll
    for (int h = 0; h < 2; ++h) {
        float a0=0.f, a1=0.f, a2=0.f, a3=0.f;
        #pragma unroll
        for (int cn = 0; cn < 8; ++cn) {
            float w = wt[h][cn];
            a0 = fmaf(v[h][cn].x, w, a0);
            a1 = fmaf(v[h][cn].y, w, a1);
            a2 = fmaf(v[h][cn].z, w, a2);
            a3 = fmaf(v[h][cn].w, w, a3);
        }
        float sc = erff(rsqrtf(8.0f*(float)(l0+h)*crf + 1e-12f));
        f[h*4+0] = a0*sc; f[h*4+1] = a1*sc; f[h*4+2] = a2*sc; f[h*4+3] = a3*sc;
    }
}

// split f[8] into bf16 hi/lo planes and store as two 16B vectors
__device__ __forceinline__ void store_split8(const float f[8],
                                             ushort* __restrict__ fh,
                                             ushort* __restrict__ fl) {
    bf16x8 h8, l8;
    #pragma unroll
    for (int j = 0; j < 8; ++j) {
        short2 sp = tsplit(f[j]);
        h8[j] = sp.x; l8[j] = sp.y;
    }
    *reinterpret_cast<bf16x8*>(fh) = h8;
    *reinterpret_cast<bf16x8*>(fl) = l8;
}

// ---------------- Kernel 1: zero + geometry + hash levels 0..3 ----------------
// Levels 0-3 footprint ~2.7MB < 4MB/XCD L2; their gather latency hides under
// the fp64 geometry VALU work (geomhash history: VALUBusy ~10%).
__global__ void __launch_bounds__(256) geom03_kernel(
    const float* __restrict__ vertices,
    const int*   __restrict__ indices,
    const float* __restrict__ center,
    const float* __restrict__ tables,
    float* __restrict__ aux,
    ushort* __restrict__ feats_hi,
    ushort* __restrict__ feats_lo,
    float* __restrict__ out, int T, int V)
{
    int t = blockIdx.x * blockDim.x + threadIdx.x;
    if (t < V) out[t] = 0.0f;     // fold zero_alpha in (V < grid span)
    if (t >= T) return;

    double p[4][3];
    #pragma unroll
    for (int v = 0; v < 4; ++v) {
        int vid = indices[t*4+v];
        p[v][0] = (double)vertices[vid*3+0];
        p[v][1] = (double)vertices[vid*3+1];
        p[v][2] = (double)vertices[vid*3+2];
    }

    double A[3][3], bb[3];
    double v0sq = p[0][0]*p[0][0] + p[0][1]*p[0][1] + p[0][2]*p[0][2];
    #pragma unroll
    for (int i = 0; i < 3; ++i) {
        #pragma unroll
        for (int j = 0; j < 3; ++j)
            A[i][j] = 2.0*(p[i+1][j] - p[0][j]) + (i==j ? 1e-6 : 0.0);
        bb[i] = p[i+1][0]*p[i+1][0] + p[i+1][1]*p[i+1][1] + p[i+1][2]*p[i+1][2] - v0sq;
    }
    double c[3];
    solve3d(A, bb, c);
    double dx0 = c[0]-p[0][0], dy0 = c[1]-p[0][1], dz0 = c[2]-p[0][2];
    double radius = sqrt(dx0*dx0 + dy0*dy0 + dz0*dz0);

    double E[3][3];
    #pragma unroll
    for (int i = 0; i < 3; ++i)
        #pragma unroll
        for (int j = 0; j < 3; ++j)
            E[i][j] = p[i+1][j] - p[0][j];
    double M[3][3], rhs[3];
    #pragma unroll
    for (int i = 0; i < 3; ++i) {
        #pragma unroll
        for (int k = 0; k < 3; ++k)
            M[i][k] = E[i][0]*E[k][0] + E[i][1]*E[k][1] + E[i][2]*E[k][2] + (i==k ? 1e-6 : 0.0);
        rhs[i] = E[i][0]*dx0 + E[i][1]*dy0 + E[i][2]*dz0;
    }
    double lam[3];
    solve3d(M, rhs, lam);
    double bary[4];
    bary[0] = 1.0 - lam[0] - lam[1] - lam[2];
    bary[1] = lam[0]; bary[2] = lam[1]; bary[3] = lam[2];
    double bs = 0.0;
    #pragma unroll
    for (int v = 0; v < 4; ++v) {
        bary[v] = fmin(fmax(bary[v], 0.0), 1.0);
        bs += bary[v];
    }
    bs = fmax(bs, 1e-6);
    double cc[3];
    #pragma unroll
    for (int j = 0; j < 3; ++j)
        cc[j] = (bary[0]*p[0][j] + bary[1]*p[1][j] + bary[2]*p[2][j] + bary[3]*p[3][j]) / bs;

    double xv[3];
    xv[0] = (cc[0] - (double)center[0]) * 0.5;
    xv[1] = (cc[1] - (double)center[1]) * 0.5;
    xv[2] = (cc[2] - (double)center[2]) * 0.5;
    double nrm = sqrt(xv[0]*xv[0] + xv[1]*xv[1] + xv[2]*xv[2]);
    double n = fmax(nrm, 1e-9);
    double cv[3], cs;
    if (n <= 1.0) {
        cv[0]=xv[0]; cv[1]=xv[1]; cv[2]=xv[2];
        cs = radius * 0.5;
    } else {
        double f = (2.0 - 1.0/n) / n;
        cv[0]=xv[0]*f; cv[1]=xv[1]*f; cv[2]=xv[2]*f;
        cs = radius * 0.5 / (n*n);
    }
    float crf = (float)(cs * 0.5);  // SCALE_MULTI

    float px = fminf(fmaxf((float)(cv[0]*0.25 + 0.5), 0.0f), 1.0f - 1e-6f);
    float py = fminf(fmaxf((float)(cv[1]*0.25 + 0.5), 0.0f), 1.0f - 1e-6f);
    float pz = fminf(fmaxf((float)(cv[2]*0.25 + 0.5), 0.0f), 1.0f - 1e-6f);

    float el = 0.0f;
    #pragma unroll
    for (int a = 0; a < 3; ++a)
        #pragma unroll
        for (int bq = a+1; bq < 4; ++bq) {
            float ddx = (float)(p[a][0]-p[bq][0]);
            float ddy = (float)(p[a][1]-p[bq][1]);
            float ddz = (float)(p[a][2]-p[bq][2]);
            el = fmaxf(el, sqrtf(ddx*ddx + ddy*ddy + ddz*ddz));
        }

    size_t st = (size_t)T;
    aux[0*st + t] = px;
    aux[1*st + t] = py;
    aux[2*st + t] = pz;
    aux[3*st + t] = crf;
    aux[4*st + t] = (float)cc[0];
    aux[5*st + t] = (float)cc[1];
    aux[6*st + t] = (float)cc[2];
    aux[7*st + t] = el;

    const float4* tb4 = reinterpret_cast<const float4*>(tables);
    ushort* fh = feats_hi + (size_t)t*NIN;
    ushort* fl = feats_lo + (size_t)t*NIN;
    float f01[8], f23[8];
    enc2(tb4, px, py, pz, crf, 0, f01);
    enc2(tb4, px, py, pz, crf, 2, f23);
    store_split8(f01, fh, fl);
    store_split8(f23, fh + 8, fl + 8);
}

// ---------------- Kernel 2 (x3): hash levels (L0, L0+1) ----------------
template<int L0>
__global__ void __launch_bounds__(256) hash_pass_kernel(
    const float* __restrict__ tables,
    const float* __restrict__ aux,
    ushort* __restrict__ feats_hi,
    ushort* __restrict__ feats_lo, int T)
{
    int t = blockIdx.x * blockDim.x + threadIdx.x;
    if (t >= T) return;
    size_t st = (size_t)T;
    float px = aux[0*st + t];
    float py = aux[1*st + t];
    float pz = aux[2*st + t];
    float crf = aux[3*st + t];
    const float4* tb4 = reinterpret_cast<const float4*>(tables);

    float f[8];
    enc2(tb4, px, py, pz, crf, L0, f);
    store_split8(f, feats_hi + (size_t)t*NIN + L0*4, feats_lo + (size_t)t*NIN + L0*4);
}

// ---------------- Kernel 3: MFMA MLP + epilogue (weights in LDS, pure bf16-rn) ----------------
__global__ void __launch_bounds__(256, 4) mlp_mfma_kernel(
    const ushort* __restrict__ feats_hi,
    const ushort* __restrict__ feats_lo,
    const float* __restrict__ aux,
    const float* __restrict__ vertices,
    const int*   __restrict__ indices,
    const float* __restrict__ W1, const float* __restrict__ b1,
    const float* __restrict__ W2, const float* __restrict__ b2,
    const float* __restrict__ W3, const float* __restrict__ b3,
    float* __restrict__ out, int T, int V)
{
    __shared__ __align__(16) float hts[4][16][LDP];   // 17.4 KB
    __shared__ bf16x8 sW1[8*64];   // 8 KB
    __shared__ bf16x8 sW2[8*64];   // 8 KB
    __shared__ bf16x8 sW3[2*64];   // 2 KB

    const int tid  = threadIdx.x;
    const int wid  = tid >> 6;
    const int lane = tid & 63;
    const int r    = lane & 15;
    const int g    = lane >> 4;

    for (int slot = tid; slot < 8*64; slot += 256) {
        int set = slot >> 6, l = slot & 63;
        int s = set >> 2, nt = set & 3;
        int rr = l & 15, gg = l >> 4;
        bf16x8 h;
        #pragma unroll
        for (int j = 0; j < 8; ++j) {
            int k = s*32 + gg*8 + j;
            float w = (k < NIN) ? W1[k*NHID + nt*16 + rr] : 0.0f;
            h[j] = (short)f2bf(w);
        }
        sW1[slot] = h;
    }
    for (int slot = tid; slot < 8*64; slot += 256) {
        int set = slot >> 6, l = slot & 63;
        int s = set >> 2, nt = set & 3;
        int rr = l & 15, gg = l >> 4;
        bf16x8 h;
        #pragma unroll
        for (int j = 0; j < 8; ++j) {
            int k = s*32 + gg*8 + j;
            h[j] = (short)f2bf(W2[k*NHID + nt*16 + rr]);
        }
        sW2[slot] = h;
    }
    for (int slot = tid; slot < 2*64; slot += 256) {
        int s = slot >> 6, l = slot & 63;
        int rr = l & 15, gg = l >> 4;
        bf16x8 h;
        #pragma unroll
        for (int j = 0; j < 8; ++j) {
            int k = s*32 + gg*8 + j;
            float w = (rr < 13) ? W3[k*13 + rr] : 0.0f;
            h[j] = (short)f2bf(w);
        }
        sW3[slot] = h;
    }
    __syncthreads();

    float b1v[4], b2v[4];
    #pragma unroll
    for (int nt = 0; nt < 4; ++nt) { b1v[nt] = b1[nt*16 + r]; b2v[nt] = b2[nt*16 + r]; }
    float b3v = (r < 13) ? b3[r] : 0.0f;

    const size_t st = (size_t)T;
    const int nmt = (T + 15) >> 4;
    const int gw = blockIdx.x * 4 + wid;
    const int gstride = gridDim.x * 4;
    const bf16x8 zfrag = {0,0,0,0,0,0,0,0};

    if (gw >= nmt) return;

    bf16x8 ah0, al0, ah1;
    {
        int trow = gw*16 + r;
        bool rowok = trow < T;
        const ushort* fh = feats_hi + (size_t)trow * NIN;
        const ushort* fl = feats_lo + (size_t)trow * NIN;
        ah0 = rowok ? *reinterpret_cast<const bf16x8*>(fh + g*8) : zfrag;
        al0 = rowok ? *reinterpret_cast<const bf16x8*>(fl + g*8) : zfrag;
        ah1 = (rowok && g == 0) ? *reinterpret_cast<const bf16x8*>(fh + 32) : zfrag;
    }

    for (int mt = gw; mt < nmt; mt += gstride) {
        const int t0 = mt * 16;

        const int te = t0 + (lane >> 2);
        const int ev = lane & 3;
        const bool teok = te < T;
        int vid = teok ? indices[te*4 + ev] : 0;
        float el  = teok ? aux[7*st + te] : 0.0f;
        float cc0 = teok ? aux[4*st + te] : 0.0f;
        float cc1 = teok ? aux[5*st + te] : 0.0f;
        float cc2 = teok ? aux[6*st + te] : 0.0f;

        __builtin_amdgcn_s_setprio(1);
        #pragma unroll
        for (int nt = 0; nt < 4; ++nt) {
            f32x4 acc = {0.f, 0.f, 0.f, 0.f};
            acc = __builtin_amdgcn_mfma_f32_16x16x32_bf16(ah0, sW1[nt*64 + lane],     acc, 0, 0, 0);
            acc = __builtin_amdgcn_mfma_f32_16x16x32_bf16(al0, sW1[nt*64 + lane],     acc, 0, 0, 0);
            acc = __builtin_amdgcn_mfma_f32_16x16x32_bf16(ah1, sW1[(4+nt)*64 + lane], acc, 0, 0, 0);
            #pragma unroll
            for (int q = 0; q < 4; ++q)
                hts[wid][g*4 + q][nt*16 + r] = selu_f(acc[q] + b1v[nt]);
        }
        __builtin_amdgcn_s_setprio(0);

        const int mtn = mt + gstride;
        bf16x8 nah0 = zfrag, nal0 = zfrag, nah1 = zfrag;
        if (mtn < nmt) {
            int trow = mtn*16 + r;
            bool rowok = trow < T;
            const ushort* fh = feats_hi + (size_t)trow * NIN;
            const ushort* fl = feats_lo + (size_t)trow * NIN;
            if (rowok) {
                nah0 = *reinterpret_cast<const bf16x8*>(fh + g*8);
                nal0 = *reinterpret_cast<const bf16x8*>(fl + g*8);
                if (g == 0) nah1 = *reinterpret_cast<const bf16x8*>(fh + 32);
            }
        }

        float pvx = vertices[vid*3+0];
        float pvy = vertices[vid*3+1];
        float pvz = vertices[vid*3+2];

        asm volatile("s_waitcnt lgkmcnt(0)" ::: "memory");

        bf16x8 a2[2];
        #pragma unroll
        for (int s = 0; s < 2; ++s) {
            float4 u0 = *reinterpret_cast<const float4*>(&hts[wid][r][s*32 + g*8]);
            float4 u1 = *reinterpret_cast<const float4*>(&hts[wid][r][s*32 + g*8 + 4]);
            bf16x8 h;
            h[0] = (short)f2bf(u0.x); h[1] = (short)f2bf(u0.y);
            h[2] = (short)f2bf(u0.z); h[3] = (short)f2bf(u0.w);
            h[4] = (short)f2bf(u1.x); h[5] = (short)f2bf(u1.y);
            h[6] = (short)f2bf(u1.z); h[7] = (short)f2bf(u1.w);
            a2[s] = h;
        }
        asm volatile("s_waitcnt lgkmcnt(0)" ::: "memory");
        float h2v[4][4];
        __builtin_amdgcn_s_setprio(1);
        #pragma unroll
        for (int nt = 0; nt < 4; ++nt) {
            f32x4 acc = {0.f, 0.f, 0.f, 0.f};
            #pragma unroll
            for (int s = 0; s < 2; ++s)
                acc = __builtin_amdgcn_mfma_f32_16x16x32_bf16(a2[s], sW2[(s*4+nt)*64 + lane], acc, 0, 0, 0);
            #pragma unroll
            for (int q = 0; q < 4; ++q) h2v[nt][q] = selu_f(acc[q] + b2v[nt]);
        }
        __builtin_amdgcn_s_setprio(0);
        #pragma unroll
        for (int nt = 0; nt < 4; ++nt)
            #pragma unroll
            for (int q = 0; q < 4; ++q)
                hts[wid][g*4 + q][nt*16 + r] = h2v[nt][q];
        asm volatile("s_waitcnt lgkmcnt(0)" ::: "memory");

        bf16x8 a3[2];
        #pragma unroll
        for (int s = 0; s < 2; ++s) {
            float4 u0 = *reinterpret_cast<const float4*>(&hts[wid][r][s*32 + g*8]);
            float4 u1 = *reinterpret_cast<const float4*>(&hts[wid][r][s*32 + g*8 + 4]);
            bf16x8 h;
            h[0] = (short)f2bf(u0.x); h[1] = (short)f2bf(u0.y);
            h[2] = (short)f2bf(u0.z); h[3] = (short)f2bf(u0.w);
            h[4] = (short)f2bf(u1.x); h[5] = (short)f2bf(u1.y);
            h[6] = (short)f2bf(u1.z); h[7] = (short)f2bf(u1.w);
            a3[s] = h;
        }
        asm volatile("s_waitcnt lgkmcnt(0)" ::: "memory");
        {
            f32x4 acc = {0.f, 0.f, 0.f, 0.f};
            __builtin_amdgcn_s_setprio(1);
            #pragma unroll
            for (int s = 0; s < 2; ++s)
                acc = __builtin_amdgcn_mfma_f32_16x16x32_bf16(a3[s], sW3[s*64 + lane], acc, 0, 0, 0);
            __builtin_amdgcn_s_setprio(0);
            #pragma unroll
            for (int q = 0; q < 4; ++q)
                hts[wid][g*4 + q][r] = acc[q] + b3v;
        }
        asm volatile("s_waitcnt lgkmcnt(0)" ::: "memory");

        if (teok) {
            const float* orow = hts[wid][lane >> 2];
            float4 o0 = *reinterpret_cast<const float4*>(&orow[0]);
            float4 o1 = *reinterpret_cast<const float4*>(&orow[4]);
            float4 o2 = *reinterpret_cast<const float4*>(&orow[8]);
            float o12 = orow[12];

            float dv = fminf(fmaxf(o0.x - 1.0f, -30.0f), 10.0f);
            float density = __expf(dv);
            float alpha = 1.0f - __expf(-density * el);
            int ab = __float_as_int(alpha);
            atomicMax((int*)out + vid, ab);

            float base0 = o0.y + 0.5f, base1 = o0.z + 0.5f, base2 = o0.w + 0.5f;
            float bc0 = fmaxf(base0, 0.0f), bc1 = fmaxf(base1, 0.0f), bc2 = fmaxf(base2, 0.0f);
            float g00 = bc0*fast_tanh(o1.x), g01 = bc0*fast_tanh(o1.y), g02 = bc0*fast_tanh(o1.z);
            float g10 = bc1*fast_tanh(o1.w), g11 = bc1*fast_tanh(o2.x), g12 = bc1*fast_tanh(o2.y);
            float g20 = bc2*fast_tanh(o2.z), g21 = bc2*fast_tanh(o2.w), g22 = bc2*fast_tanh(o12);

            float ox = pvx-cc0, oy = pvy-cc1, oz = pvz-cc2;
            float inv = rsqrtf(ox*ox + oy*oy + oz*oz + 1e-8f);
            float q0 = ox*inv, q1 = oy*inv, q2 = oz*inv;
            float* vout = out + V + (size_t)te * 12 + ev*3;
            vout[0] = base0 + g00*q0 + g01*q1 + g02*q2;
            vout[1] = base1 + g10*q0 + g11*q1 + g12*q2;
            vout[2] = base2 + g20*q0 + g21*q1 + g22*q2;
        }
        asm volatile("s_waitcnt lgkmcnt(0)" ::: "memory");

        ah0 = nah0; al0 = nal0; ah1 = nah1;
    }
}

// ---------------- Fallback fused kernel (used only if ws is too small) ----------------
__global__ void __launch_bounds__(256) zero_alpha_kernel(float* out, int V) {
    int i = blockIdx.x * blockDim.x + threadIdx.x;
    if (i < V) out[i] = 0.0f;
}

__global__ void __launch_bounds__(256) tet_forward_fused(
    const float* __restrict__ vertices,
    const int*   __restrict__ indices,
    const float* __restrict__ center,
    const float* __restrict__ tables,
    const float* __restrict__ W1, const float* __restrict__ b1,
    const float* __restrict__ W2, const float* __restrict__ b2,
    const float* __restrict__ W3, const float* __restrict__ b3,
    float* __restrict__ out, int T, int V)
{
    int t = blockIdx.x * blockDim.x + threadIdx.x;
    if (t >= T) return;

    double p[4][3];
    int vv[4];
    #pragma unroll
    for (int v = 0; v < 4; ++v) {
        vv[v] = indices[t*4+v];
        p[v][0] = (double)vertices[vv[v]*3+0];
        p[v][1] = (double)vertices[vv[v]*3+1];
        p[v][2] = (double)vertices[vv[v]*3+2];
    }
    double A[3][3], bb[3];
    double v0sq = p[0][0]*p[0][0] + p[0][1]*p[0][1] + p[0][2]*p[0][2];
    #pragma unroll
    for (int i = 0; i < 3; ++i) {
        #pragma unroll
        for (int j = 0; j < 3; ++j)
            A[i][j] = 2.0*(p[i+1][j] - p[0][j]) + (i==j ? 1e-6 : 0.0);
        bb[i] = p[i+1][0]*p[i+1][0] + p[i+1][1]*p[i+1][1] + p[i+1][2]*p[i+1][2] - v0sq;
    }
    double c[3];
    solve3d(A, bb, c);
    double dx0 = c[0]-p[0][0], dy0 = c[1]-p[0][1], dz0 = c[2]-p[0][2];
    double radius = sqrt(dx0*dx0 + dy0*dy0 + dz0*dz0);
    double E[3][3];
    #pragma unroll
    for (int i = 0; i < 3; ++i)
        #pragma unroll
        for (int j = 0; j < 3; ++j)
            E[i][j] = p[i+1][j] - p[0][j];
    double M[3][3], rhs[3];
    #pragma unroll
    for (int i = 0; i < 3; ++i) {
        #pragma unroll
        for (int k = 0; k < 3; ++k)
            M[i][k] = E[i][0]*E[k][0] + E[i][1]*E[k][1] + E[i][2]*E[k][2] + (i==k ? 1e-6 : 0.0);
        rhs[i] = E[i][0]*dx0 + E[i][1]*dy0 + E[i][2]*dz0;
    }
    double lam[3];
    solve3d(M, rhs, lam);
    double bary[4];
    bary[0] = 1.0 - lam[0] - lam[1] - lam[2];
    bary[1] = lam[0]; bary[2] = lam[1]; bary[3] = lam[2];
    double bs = 0.0;
    #pragma unroll
    for (int v = 0; v < 4; ++v) { bary[v] = fmin(fmax(bary[v], 0.0), 1.0); bs += bary[v]; }
    bs = fmax(bs, 1e-6);
    double cc[3];
    #pragma unroll
    for (int j = 0; j < 3; ++j)
        cc[j] = (bary[0]*p[0][j] + bary[1]*p[1][j] + bary[2]*p[2][j] + bary[3]*p[3][j]) / bs;
    double xv[3];
    xv[0] = (cc[0] - (double)center[0]) * 0.5;
    xv[1] = (cc[1] - (double)center[1]) * 0.5;
    xv[2] = (cc[2] - (double)center[2]) * 0.5;
    double nrm = sqrt(xv[0]*xv[0] + xv[1]*xv[1] + xv[2]*xv[2]);
    double n = fmax(nrm, 1e-9);
    double cv[3], cs;
    if (n <= 1.0) { cv[0]=xv[0]; cv[1]=xv[1]; cv[2]=xv[2]; cs = radius * 0.5; }
    else { double f = (2.0 - 1.0/n) / n; cv[0]=xv[0]*f; cv[1]=xv[1]*f; cv[2]=xv[2]*f; cs = radius * 0.5 / (n*n); }
    float crf = (float)(cs * 0.5);
    float pos0 = fminf(fmaxf((float)(cv[0]*0.25 + 0.5), 0.0f), 1.0f - 1e-6f);
    float pos1 = fminf(fmaxf((float)(cv[1]*0.25 + 0.5), 0.0f), 1.0f - 1e-6f);
    float pos2 = fminf(fmaxf((float)(cv[2]*0.25 + 0.5), 0.0f), 1.0f - 1e-6f);

    float h0[NIN];
    float res = 16.0f;
    #pragma unroll
    for (int l = 0; l < NLVL; ++l) {
        float x0 = pos0*res, x1 = pos1*res, x2 = pos2*res;
        float f0 = floorf(x0), f1 = floorf(x1), f2 = floorf(x2);
        float w0 = x0-f0, w1 = x1-f1, w2 = x2-f2;
        unsigned i0 = (unsigned)f0, i1 = (unsigned)f1, i2 = (unsigned)f2;
        float a0=0.f, a1=0.f, a2=0.f, a3=0.f;
        #pragma unroll
        for (int cn = 0; cn < 8; ++cn) {
            unsigned cx = (unsigned)(cn & 1), cy = (unsigned)((cn >> 1) & 1), cz = (unsigned)((cn >> 2) & 1);
            unsigned hh = ((i0 + cx) * 1u) ^ ((i1 + cy) * 2654435761u) ^ ((i2 + cz) * 805459861u);
            hh &= 65535u;
            float wt = (cx ? w0 : 1.0f - w0) * (cy ? w1 : 1.0f - w1) * (cz ? w2 : 1.0f - w2);
            const float4 tv = *reinterpret_cast<const float4*>(tables + ((size_t)l*TBL + hh)*4);
            a0 = fmaf(tv.x, wt, a0); a1 = fmaf(tv.y, wt, a1);
            a2 = fmaf(tv.z, wt, a2); a3 = fmaf(tv.w, wt, a3);
        }
        float sc = erff(rsqrtf(8.0f*(float)l*crf + 1e-12f));
        h0[l*4+0] = a0*sc; h0[l*4+1] = a1*sc; h0[l*4+2] = a2*sc; h0[l*4+3] = a3*sc;
        res *= 2.0f;
    }

    float h1[NHID];
    #pragma unroll
    for (int j = 0; j < NHID; ++j) h1[j] = b1[j];
    #pragma unroll
    for (int i = 0; i < NIN; ++i) {
        float hi = h0[i];
        #pragma unroll
        for (int j = 0; j < NHID; ++j) h1[j] = fmaf(hi, W1[i*NHID + j], h1[j]);
    }
    #pragma unroll
    for (int j = 0; j < NHID; ++j) h1[j] = selu_f(h1[j]);

    float o[13];
    #pragma unroll
    for (int k = 0; k < 13; ++k) o[k] = b3[k];
    #pragma unroll
    for (int half = 0; half < 2; ++half) {
        float h2h[32];
        #pragma unroll
        for (int jj = 0; jj < 32; ++jj) h2h[jj] = b2[half*32 + jj];
        #pragma unroll
        for (int i = 0; i < NHID; ++i) {
            float hi = h1[i];
            #pragma unroll
            for (int jj = 0; jj < 32; ++jj)
                h2h[jj] = fmaf(hi, W2[i*NHID + half*32 + jj], h2h[jj]);
        }
        #pragma unroll
        for (int jj = 0; jj < 32; ++jj) {
            float hv = selu_f(h2h[jj]);
            #pragma unroll
            for (int k = 0; k < 13; ++k)
                o[k] = fmaf(hv, W3[(half*32 + jj)*13 + k], o[k]);
        }
    }

    float dv = fminf(fmaxf(o[0] - 1.0f, -30.0f), 10.0f);
    float density = __expf(dv);
    float el = 0.0f;
    #pragma unroll
    for (int a = 0; a < 3; ++a)
        #pragma unroll
        for (int bq = a+1; bq < 4; ++bq) {
            float ddx = (float)(p[a][0]-p[bq][0]);
            float ddy = (float)(p[a][1]-p[bq][1]);
            float ddz = (float)(p[a][2]-p[bq][2]);
            el = fmaxf(el, sqrtf(ddx*ddx + ddy*ddy + ddz*ddz));
        }
    float alpha = 1.0f - __expf(-density * el);
    int ab = __float_as_int(alpha);
    atomicMax((int*)out + vv[0], ab);
    atomicMax((int*)out + vv[1], ab);
    atomicMax((int*)out + vv[2], ab);
    atomicMax((int*)out + vv[3], ab);

    float base0 = o[1] + 0.5f, base1 = o[2] + 0.5f, base2 = o[3] + 0.5f;
    float bc0 = fmaxf(base0, 0.0f), bc1 = fmaxf(base1, 0.0f), bc2 = fmaxf(base2, 0.0f);
    float g00 = bc0*fast_tanh(o[4]),  g01 = bc0*fast_tanh(o[5]),  g02 = bc0*fast_tanh(o[6]);
    float g10 = bc1*fast_tanh(o[7]),  g11 = bc1*fast_tanh(o[8]),  g12 = bc1*fast_tanh(o[9]);
    float g20 = bc2*fast_tanh(o[10]), g21 = bc2*fast_tanh(o[11]), g22 = bc2*fast_tanh(o[12]);

    float* vout = out + V + (size_t)t * 12;
    #pragma unroll
    for (int v = 0; v < 4; ++v) {
        float ox = (float)(p[v][0]-cc[0]), oy = (float)(p[v][1]-cc[1]), oz = (float)(p[v][2]-cc[2]);
        float inv = rsqrtf(ox*ox + oy*oy + oz*oz + 1e-8f);
        float q0 = ox*inv, q1 = oy*inv, q2 = oz*inv;
        vout[v*3+0] = base0 + g00*q0 + g01*q1 + g02*q2;
        vout[v*3+1] = base1 + g10*q0 + g11*q1 + g12*q2;
        vout[v*3+2] = base2 + g20*q0 + g21*q1 + g22*q2;
    }
}

extern "C" void kernel_launch(void* const* d_in, const int* in_sizes, int n_in,
                              void* d_out, int out_size, void* d_ws, size_t ws_size,
                              hipStream_t stream) {
    const float* vertices = (const float*)d_in[0];
    const int*   indices  = (const int*)d_in[1];
    const float* center   = (const float*)d_in[2];
    const float* tables   = (const float*)d_in[3];
    const float* W1 = (const float*)d_in[4];
    const float* b1 = (const float*)d_in[5];
    const float* W2 = (const float*)d_in[6];
    const float* b2 = (const float*)d_in[7];
    const float* W3 = (const float*)d_in[8];
    const float* b3 = (const float*)d_in[9];
    int V = in_sizes[0] / 3;
    int T = in_sizes[1] / 4;
    float* out = (float*)d_out;

    // ws: aux f32[8][T] + feats_hi u16[T][40] + feats_lo u16[T][40]
    size_t need = (size_t)T * 48 * sizeof(float);
    int span = (T > V) ? T : V;
    dim3 grid((span + 255) / 256), gridT((T + 255) / 256), blk(256);
    if (ws_size >= need) {
        float* aux = (float*)d_ws;
        ushort* feats_hi = (ushort*)(aux + (size_t)T * 8);
        ushort* feats_lo = feats_hi + (size_t)T * NIN;
        hipLaunchKernelGGL(geom03_kernel, grid, blk, 0, stream,
                           vertices, indices, center, tables, aux, feats_hi, feats_lo, out, T, V);
        hipLaunchKernelGGL((hash_pass_kernel<4>), gridT, blk, 0, stream, tables, aux, feats_hi, feats_lo, T);
        hipLaunchKernelGGL((hash_pass_kernel<6>), gridT, blk, 0, stream, tables, aux, feats_hi, feats_lo, T);
        hipLaunchKernelGGL((hash_pass_kernel<8>), gridT, blk, 0, stream, tables, aux, feats_hi, feats_lo, T);
        hipLaunchKernelGGL(mlp_mfma_kernel, dim3(1024), blk, 0, stream, feats_hi, feats_lo, aux,
                           vertices, indices, W1, b1, W2, b2, W3, b3, out, T, V);
    } else {
        hipLaunchKernelGGL(zero_alpha_kernel, dim3((V + 255) / 256), blk, 0, stream, out, V);
        hipLaunchKernelGGL(tet_forward_fused, gridT, blk, 0, stream,
                           vertices, indices, center, tables, W1, b1, W2, b2, W3, b3, out, T, V);
    }
}